// Round 10
// baseline (897.252 us; speedup 1.0000x reference)
//
#include <hip/hip_runtime.h>
#include <stdint.h>

// Problem constants
#define NB   32
#define TSEQ 4096
#define DD   256
#define PP   2
#define KK   17
#define LL   3
#define NHH  8
#define HDD  32
#define FFD  2048
#define HIDD 128
#define ROWS 1088                    // B*P*K
#define SCALE 0.17677669529663689f   // 1/sqrt(32)

typedef __attribute__((ext_vector_type(4))) float f32x4;
typedef __attribute__((ext_vector_type(8))) short bf16x8;

static __device__ __forceinline__ unsigned cvtpk(float lo, float hi) {
  unsigned r;
  asm volatile("v_cvt_pk_bf16_f32 %0, %1, %2" : "=v"(r) : "v"(lo), "v"(hi));
  return r;
}
static __device__ __forceinline__ unsigned short f2bf(float f) {
  unsigned int x = __float_as_uint(f);
  return (unsigned short)((x + 0x7fffu + ((x >> 16) & 1u)) >> 16);
}
static __device__ __forceinline__ void gload_lds16(const void* g, void* l) {
  __builtin_amdgcn_global_load_lds(
      (const __attribute__((address_space(1))) unsigned int*)g,
      (__attribute__((address_space(3))) unsigned int*)l, 16, 0, 0);
}

// ---------- batched fp32 -> bf16 convert (8 jobs in one launch) ----------
struct CvtJob { const float* src; unsigned short* dst; int n; };
struct CvtJobs8 { CvtJob j[8]; };
__global__ __launch_bounds__(256) void cvt_multi_kernel(CvtJobs8 jobs) {
#pragma unroll
  for (int jj = 0; jj < 8; ++jj) {
    const float* src = jobs.j[jj].src;
    unsigned short* dst = jobs.j[jj].dst;
    const int n8 = jobs.j[jj].n >> 3;
    for (int i = blockIdx.x * 256 + threadIdx.x; i < n8; i += gridDim.x * 256) {
      const float4 f0 = *reinterpret_cast<const float4*>(src + i * 8);
      const float4 f1 = *reinterpret_cast<const float4*>(src + i * 8 + 4);
      uint4 st;
      st.x = cvtpk(f0.x, f0.y); st.y = cvtpk(f0.z, f0.w);
      st.z = cvtpk(f1.x, f1.y); st.w = cvtpk(f1.z, f1.w);
      *reinterpret_cast<uint4*>(dst + i * 8) = st;
    }
  }
}

// ---------- merged small prep: init_x (1088) + bqk (24) + bvo (3) ----------
__global__ __launch_bounds__(256) void prep_small_kernel(
    const float* __restrict__ person_q, const float* __restrict__ key_q,
    const float* __restrict__ ca_in_w, const float* __restrict__ ca_in_b,
    const float* __restrict__ ca_out_w, const float* __restrict__ ca_out_b,
    float* __restrict__ x, unsigned short* __restrict__ x_bf,
    float* __restrict__ bqk, float* __restrict__ bvo) {
  const int bx = blockIdx.x, tid = threadIdx.x;
  if (bx < ROWS) {
    const int p = (bx / KK) & 1, k = bx % KK;
    const float v = person_q[p * DD + tid] + key_q[k * DD + tid];
    x[(size_t)bx * DD + tid] = v;
    x_bf[(size_t)bx * DD + tid] = f2bf(v);
  } else if (bx < ROWS + 24) {
    const int b2 = bx - ROWS;
    const int l = b2 >> 3, h = b2 & 7;
    const float* Wk = ca_in_w + (size_t)l * 196608 + (size_t)(256 + h * 32) * 256;
    const float* bq = ca_in_b + l * 768 + h * 32;
    float acc = 0.f;
#pragma unroll
    for (int j = 0; j < 32; ++j) acc += bq[j] * Wk[(size_t)j * 256 + tid];
    bqk[(size_t)l * 2048 + h * 256 + tid] = acc * SCALE;
  } else {
    const int l = bx - ROWS - 24;
    float acc = ca_out_b[l * 256 + tid];
    for (int j = 0; j < 256; ++j)
      acc += ca_out_w[(size_t)l * 65536 + (size_t)tid * 256 + j] * ca_in_b[l * 768 + 512 + j];
    bvo[l * 256 + tid] = acc;
  }
}

// ---------- generic fp32 GEMM (final fc only) ----------
__global__ __launch_bounds__(256) void gemm_kernel(
    const float* __restrict__ X, const float* __restrict__ W,
    const float* __restrict__ bias, const float* __restrict__ R,
    float* __restrict__ Y, int M, int N, int K, int wstride, int relu) {
  __shared__ float As[16][68];
  __shared__ float Bs[16][68];
  const int tid = threadIdx.x;
  const int m0 = blockIdx.y * 64, n0 = blockIdx.x * 64;
  const int tr = tid >> 4, tc = tid & 15;
  const int lr = tid >> 2, lk = (tid & 3) << 2;
  float acc[4][4] = {{0.f, 0.f, 0.f, 0.f}, {0.f, 0.f, 0.f, 0.f},
                     {0.f, 0.f, 0.f, 0.f}, {0.f, 0.f, 0.f, 0.f}};
  for (int k0 = 0; k0 < K; k0 += 16) {
    const float4 av = *reinterpret_cast<const float4*>(&X[(size_t)(m0 + lr) * K + k0 + lk]);
    int wn = n0 + lr; if (wn >= N) wn = N - 1;
    const float4 bv = *reinterpret_cast<const float4*>(&W[(size_t)wn * wstride + k0 + lk]);
    __syncthreads();
    As[lk + 0][lr] = av.x; As[lk + 1][lr] = av.y; As[lk + 2][lr] = av.z; As[lk + 3][lr] = av.w;
    Bs[lk + 0][lr] = bv.x; Bs[lk + 1][lr] = bv.y; Bs[lk + 2][lr] = bv.z; Bs[lk + 3][lr] = bv.w;
    __syncthreads();
#pragma unroll
    for (int kk = 0; kk < 16; ++kk) {
      const float4 a = *reinterpret_cast<const float4*>(&As[kk][tr << 2]);
      const float4 b = *reinterpret_cast<const float4*>(&Bs[kk][tc << 2]);
      const float aa[4] = {a.x, a.y, a.z, a.w};
      const float bb[4] = {b.x, b.y, b.z, b.w};
#pragma unroll
      for (int r = 0; r < 4; ++r)
#pragma unroll
        for (int c = 0; c < 4; ++c) acc[r][c] += aa[r] * bb[c];
    }
  }
#pragma unroll
  for (int r = 0; r < 4; ++r) {
    const int m = m0 + (tr << 2) + r;
#pragma unroll
    for (int c = 0; c < 4; ++c) {
      const int n = n0 + (tc << 2) + c;
      if (n < N) {
        float o = acc[r][c];
        if (bias) o += bias[n];
        if (relu) o = fmaxf(o, 0.f);
        if (R) o += R[(size_t)m * N + n];
        Y[(size_t)m * N + n] = o;
      }
    }
  }
}

// ---------- bf16 MFMA GEMM: Y = act(Xbf @ Wbf^T + bias) [+ R] ----------
// M,N,K multiples of 64. 64x64 tile, 4 waves. (single-buffered: best measured)
__global__ __launch_bounds__(256) void gemm_bf16_kernel(
    const unsigned short* __restrict__ Xbf, const unsigned short* __restrict__ Wbf,
    const float* __restrict__ bias, const float* __restrict__ R,
    float* __restrict__ Yf, unsigned short* __restrict__ Ybf,
    int M, int N, int K, int wstride, int relu) {
  __shared__ unsigned short Xs[64 * 64];
  __shared__ unsigned short Ws[64 * 64];
  const int tid = threadIdx.x, lane = tid & 63, w = tid >> 6;
  const int g = lane >> 4, q16 = lane & 15;
  const int m0 = blockIdx.y * 64, n0 = blockIdx.x * 64;
  f32x4 acc[4];
#pragma unroll
  for (int nt = 0; nt < 4; ++nt) acc[nt] = (f32x4){0.f, 0.f, 0.f, 0.f};

  for (int k0 = 0; k0 < K; k0 += 64) {
    __syncthreads();
#pragma unroll
    for (int j = 0; j < 2; ++j) {
      const int cc = w * 2 + j;
      const int row = cc * 8 + (lane >> 3);
      const int sc = (lane & 7) ^ (row & 7);
      gload_lds16(Xbf + (size_t)(m0 + row) * K + k0 + sc * 8, &Xs[cc * 512]);
      gload_lds16(Wbf + (size_t)(n0 + row) * wstride + k0 + sc * 8, &Ws[cc * 512]);
    }
    asm volatile("s_waitcnt vmcnt(0)" ::: "memory");
    __syncthreads();
    const int arow = w * 16 + q16;
#pragma unroll
    for (int ks = 0; ks < 2; ++ks) {
      const bf16x8 a = *reinterpret_cast<const bf16x8*>(
          &Xs[arow * 64 + ((((ks << 2) + g) ^ (arow & 7)) << 3)]);
#pragma unroll
      for (int nt = 0; nt < 4; ++nt) {
        const int brow = nt * 16 + q16;
        const bf16x8 bfr = *reinterpret_cast<const bf16x8*>(
            &Ws[brow * 64 + ((((ks << 2) + g) ^ (brow & 7)) << 3)]);
        acc[nt] = __builtin_amdgcn_mfma_f32_16x16x32_bf16(a, bfr, acc[nt], 0, 0, 0);
      }
    }
  }
#pragma unroll
  for (int nt = 0; nt < 4; ++nt) {
    const int n = n0 + nt * 16 + q16;
    const float bv = bias ? bias[n] : 0.f;
#pragma unroll
    for (int r = 0; r < 4; ++r) {
      const int m = m0 + w * 16 + g * 4 + r;
      float o = acc[nt][r] + bv;
      if (relu) o = fmaxf(o, 0.f);
      if (R) o += R[(size_t)m * N + n];
      if (Yf) Yf[(size_t)m * N + n] = o;
      if (Ybf) Ybf[(size_t)m * N + n] = f2bf(o);
    }
  }
}

// ---------- fused bf16 GEMM (N=256) + residual + LayerNorm ----------
// Tile 64 rows x 256 cols, grid = ROWS/64 = 17. Wave w owns rows [w*16,w*16+16)
// across ALL 256 cols -> LN is a pure in-wave shfl reduction (no barrier).
// x <- LN(x + Xbf@Wbf^T + bias); writes fp32 x and bf16 x_bf.
__global__ __launch_bounds__(256) void gemm_bf16_ln_kernel(
    const unsigned short* __restrict__ Xbf, const unsigned short* __restrict__ Wbf,
    const float* __restrict__ bias, const float* __restrict__ lnw,
    const float* __restrict__ lnb, float* __restrict__ xio,
    unsigned short* __restrict__ x_bf, int K, int wstride) {
  __shared__ unsigned short Xs[64 * 64];     // 8 KB
  __shared__ unsigned short Ws[256 * 64];    // 32 KB
  __shared__ float bias_s[256], lnw_s[256], lnb_s[256];
  const int tid = threadIdx.x, lane = tid & 63, w = tid >> 6;
  const int g = lane >> 4, q16 = lane & 15;
  const int m0 = blockIdx.x * 64;
  bias_s[tid] = bias[tid];
  lnw_s[tid] = lnw[tid];
  lnb_s[tid] = lnb[tid];
  f32x4 acc[16];
#pragma unroll
  for (int nt = 0; nt < 16; ++nt) acc[nt] = (f32x4){0.f, 0.f, 0.f, 0.f};

  for (int k0 = 0; k0 < K; k0 += 64) {
    __syncthreads();
    // A tile 64x64: 8 regions (2 rows... 8 rows each), wave stages 2
#pragma unroll
    for (int j = 0; j < 2; ++j) {
      const int cc = w * 2 + j;
      const int row = cc * 8 + (lane >> 3);
      const int sc = (lane & 7) ^ (row & 7);
      gload_lds16(Xbf + (size_t)(m0 + row) * K + k0 + sc * 8, &Xs[cc * 512]);
    }
    // B tile 256x64: 32 regions (8 rows each), wave stages 8
#pragma unroll
    for (int j = 0; j < 8; ++j) {
      const int cc = w * 8 + j;
      const int row = cc * 8 + (lane >> 3);
      const int sc = (lane & 7) ^ (row & 7);
      gload_lds16(Wbf + (size_t)row * wstride + k0 + sc * 8, &Ws[cc * 512]);
    }
    asm volatile("s_waitcnt vmcnt(0)" ::: "memory");
    __syncthreads();
    const int arow = w * 16 + q16;
#pragma unroll
    for (int ks = 0; ks < 2; ++ks) {
      const bf16x8 a = *reinterpret_cast<const bf16x8*>(
          &Xs[arow * 64 + ((((ks << 2) + g) ^ (arow & 7)) << 3)]);
#pragma unroll
      for (int nt = 0; nt < 16; ++nt) {
        const int brow = nt * 16 + q16;
        const bf16x8 bfr = *reinterpret_cast<const bf16x8*>(
            &Ws[brow * 64 + ((((ks << 2) + g) ^ (brow & 7)) << 3)]);
        acc[nt] = __builtin_amdgcn_mfma_f32_16x16x32_bf16(a, bfr, acc[nt], 0, 0, 0);
      }
    }
  }

  // epilogue: per lane 4 rows x 16 cols; LN per row via 16-lane shfl reduce
#pragma unroll
  for (int r = 0; r < 4; ++r) {
    const int m = m0 + w * 16 + g * 4 + r;
    float s = 0.f, s2 = 0.f;
#pragma unroll
    for (int nt = 0; nt < 16; ++nt) {
      const int n = nt * 16 + q16;
      const float o = acc[nt][r] + bias_s[n] + xio[(size_t)m * DD + n];
      acc[nt][r] = o;
      s += o; s2 += o * o;
    }
#pragma unroll
    for (int off = 1; off < 16; off <<= 1) {
      s += __shfl_xor(s, off);
      s2 += __shfl_xor(s2, off);
    }
    const float mean = s * (1.f / 256.f);
    const float var = s2 * (1.f / 256.f) - mean * mean;
    const float inv = rsqrtf(var + 1e-5f);
#pragma unroll
    for (int nt = 0; nt < 16; ++nt) {
      const int n = nt * 16 + q16;
      const float v = (acc[nt][r] - mean) * inv * lnw_s[n] + lnb_s[n];
      xio[(size_t)m * DD + n] = v;
      x_bf[(size_t)m * DD + n] = f2bf(v);
    }
  }
}

// ---------- self-attention over K=17 keypoints (bf16 out) ----------
__global__ __launch_bounds__(64) void sa_attn_kernel(
    const float* __restrict__ qkv, unsigned short* __restrict__ attn_bf) {
  const int blk = blockIdx.x;
  const int h = blk & 7, bp = blk >> 3;
  const int rowbase = bp * KK;
  const int tid = threadIdx.x;
  __shared__ float qs[KK][36], ks[KK][36], vs[KK][36];
  __shared__ float ss[KK][20];
  __shared__ float lsum[KK];
  for (int i = tid; i < KK * HDD; i += 64) {
    const int r = i >> 5, d = i & 31;
    const size_t base = (size_t)(rowbase + r) * 768 + h * 32 + d;
    qs[r][d] = qkv[base];
    ks[r][d] = qkv[base + 256];
    vs[r][d] = qkv[base + 512];
  }
  __syncthreads();
  for (int i = tid; i < KK * KK; i += 64) {
    const int q = i / KK, k = i % KK;
    float s = 0.f;
#pragma unroll
    for (int d = 0; d < HDD; ++d) s += qs[q][d] * ks[k][d];
    ss[q][k] = s * SCALE;
  }
  __syncthreads();
  if (tid < KK) {
    float m = -1e30f;
    for (int k = 0; k < KK; ++k) m = fmaxf(m, ss[tid][k]);
    float l = 0.f;
    for (int k = 0; k < KK; ++k) { const float e = __expf(ss[tid][k] - m); ss[tid][k] = e; l += e; }
    lsum[tid] = l;
  }
  __syncthreads();
  for (int i = tid; i < KK * HDD; i += 64) {
    const int q = i >> 5, d = i & 31;
    float o = 0.f;
#pragma unroll
    for (int k = 0; k < KK; ++k) o += ss[q][k] * vs[k][d];
    attn_bf[(size_t)(rowbase + q) * DD + h * 32 + d] = f2bf(o / lsum[q]);
  }
}

// ---------- merged Wqk + Wvo folding (grid 12288) ----------
__global__ __launch_bounds__(256) void wqkvo_kernel(
    const float* __restrict__ ca_in_w, const float* __restrict__ ca_out_w,
    unsigned short* __restrict__ Wqk_bf, unsigned short* __restrict__ Wvo_bf) {
  const int bx0 = blockIdx.x;
  if (bx0 < 6144) {
    const int l = bx0 >> 11, hc = bx0 & 2047;
    const int h = hc >> 8, c = hc & 255;
    const int d = threadIdx.x;
    const float* Wq = ca_in_w + (size_t)l * 196608 + (size_t)(h * 32) * 256;
    const float* Wk = ca_in_w + (size_t)l * 196608 + (size_t)(256 + h * 32) * 256;
    float acc = 0.f;
#pragma unroll
    for (int j = 0; j < 32; ++j) acc += Wk[(size_t)j * 256 + c] * Wq[(size_t)j * 256 + d];
    Wqk_bf[((size_t)l * 2048 + hc) * 256 + d] = f2bf(acc * SCALE);
  } else {
    const int bx = bx0 - 6144;
    const int h = bx & 7, dp = (bx >> 3) & 255, l = bx >> 11;
    const int c = threadIdx.x;
    const float* wout = ca_out_w + (size_t)l * 65536 + (size_t)dp * 256 + h * 32;
    const float* wv = ca_in_w + (size_t)l * 196608 + (size_t)(512 + h * 32) * 256 + c;
    float acc = 0.f;
#pragma unroll
    for (int j = 0; j < 32; ++j) acc += wout[j] * wv[(size_t)j * 256];
    Wvo_bf[((size_t)l * 256 + dp) * 2048 + h * 256 + c] = f2bf(acc);
  }
}

// ---------- prep: mem_bf[b][t][c] + memT[b][c][t] (both bf16) ----------
__global__ __launch_bounds__(256) void prep_mem_kernel(
    const float* __restrict__ memory, unsigned short* __restrict__ mem_bf,
    unsigned short* __restrict__ memT) {
  const int b = blockIdx.x >> 6, tc = blockIdx.x & 63;
  const int tid = threadIdx.x;
  __shared__ unsigned short tile[64][264];
  for (int it = 0; it < 8; ++it) {
    const int idx = it * 256 + tid;
    const int t = idx >> 5, c8 = (idx & 31) << 3;
    const size_t goff = ((size_t)b * TSEQ + tc * 64 + t) * DD + c8;
    const float4 f0 = *reinterpret_cast<const float4*>(memory + goff);
    const float4 f1 = *reinterpret_cast<const float4*>(memory + goff + 4);
    uint4 st;
    st.x = cvtpk(f0.x, f0.y); st.y = cvtpk(f0.z, f0.w);
    st.z = cvtpk(f1.x, f1.y); st.w = cvtpk(f1.z, f1.w);
    *reinterpret_cast<uint4*>(&tile[t][c8]) = st;
    *reinterpret_cast<uint4*>(mem_bf + goff) = st;
  }
  __syncthreads();
  for (int it = 0; it < 8; ++it) {
    const int idx = it * 256 + tid;
    const int c = idx >> 3, t8 = (idx & 7) << 3;
    union { unsigned short v[8]; uint4 u; } pk;
#pragma unroll
    for (int j = 0; j < 8; ++j) pk.v[j] = tile[t8 + j][c];
    *reinterpret_cast<uint4*>(&memT[((size_t)b * DD + c) * TSEQ + tc * 64 + t8]) = pk.u;
  }
}

// ---------- fused MFMA cross-attention flash (v4 — best measured: 130 µs) ----------
// grid 512: bid = h*64 + b*2 + half -> 8 heads of same (b,half) share bid%8 (XCD).
// 256 threads = 4 waves, t-tile 64, 32 tiles per block. LDS 74KB -> 2 blocks/CU.
#define PS3 72
__global__ __launch_bounds__(256, 2) void ca_fused_kernel(
    const unsigned short* __restrict__ qkeff_bf, const unsigned short* __restrict__ mem_bf,
    const unsigned short* __restrict__ memT,
    float* __restrict__ o_part, float* __restrict__ m_part, float* __restrict__ l_part) {
  const int h = blockIdx.x >> 6;
  const int b = (blockIdx.x >> 1) & 31;
  const int half = blockIdx.x & 1;
  const int tid = threadIdx.x;
  const int lane = tid & 63, w = tid >> 6;      // w in 0..3
  const int g = lane >> 4, q16 = lane & 15;

  __shared__ unsigned short mem_lds[64 * 256];    // [t][c], XOR-swizzled 16B chunks
  __shared__ unsigned short memT_lds[256 * 64];   // [c][t], XOR-swizzled 16B chunks
  __shared__ unsigned short p_lds[48 * PS3];
  __shared__ float red_m[4 * 48];                 // [w][q] transposed: conflict-free
  __shared__ float red_l[4 * 48];
  __shared__ float r_lds[48];

  // --- Q B-fragments direct bf16 (loop-invariant) ---
  bf16x8 bq[3][8];
#pragma unroll
  for (int qt = 0; qt < 3; ++qt) {
    const int ql = qt * 16 + q16;
    if (ql < 34) {
      const unsigned short* qbase = qkeff_bf + (size_t)(b * 34 + ql) * 2048 + h * 256;
#pragma unroll
      for (int ks = 0; ks < 8; ++ks)
        bq[qt][ks] = *reinterpret_cast<const bf16x8*>(qbase + ks * 32 + g * 8);
    } else {
#pragma unroll
      for (int ks = 0; ks < 8; ++ks) bq[qt][ks] = (bf16x8){0, 0, 0, 0, 0, 0, 0, 0};
    }
  }

  f32x4 ctx[3][4];
#pragma unroll
  for (int mt = 0; mt < 3; ++mt)
#pragma unroll
    for (int nt = 0; nt < 4; ++nt) ctx[mt][nt] = (f32x4){0.f, 0.f, 0.f, 0.f};
  float m_run[3] = {-1e30f, -1e30f, -1e30f};
  float l_run[3] = {0.f, 0.f, 0.f};

  const unsigned short* membb = mem_bf + (size_t)b * TSEQ * DD;
  const unsigned short* memTb = memT + (size_t)b * DD * TSEQ;

  for (int tile = 0; tile < 32; ++tile) {
    const int tbase = half * 2048 + tile * 64;
    __syncthreads();   // (A) previous tile fully consumed

    // --- stage mem tile 64x256 (32KB): 8 calls/wave, 1KB = 2 rows each ---
#pragma unroll
    for (int j = 0; j < 8; ++j) {
      const int cc = w * 8 + j;
      const int trow = cc * 2 + (lane >> 5);
      const int sc = (lane & 31) ^ (trow & 7);
      gload_lds16(membb + (size_t)(tbase + trow) * DD + sc * 8, &mem_lds[cc * 512]);
    }
    // --- stage memT tile 256x64 (32KB): 8 calls/wave, 1KB = 8 rows each ---
#pragma unroll
    for (int j = 0; j < 8; ++j) {
      const int cc = w * 8 + j;
      const int crow = cc * 8 + (lane >> 3);
      const int sc = (lane & 7) ^ (crow & 7);
      gload_lds16(memTb + (size_t)crow * TSEQ + tbase + sc * 8, &memT_lds[cc * 512]);
    }
    asm volatile("s_waitcnt vmcnt(0)" ::: "memory");
    __syncthreads();   // (B) staged

    // --- QK^T (swapped): wave w owns t-strip [w*16, w*16+16) ---
    f32x4 sacc[3];
#pragma unroll
    for (int qt = 0; qt < 3; ++qt) sacc[qt] = (f32x4){0.f, 0.f, 0.f, 0.f};
    {
      const int arow = w * 16 + q16;
      __builtin_amdgcn_s_setprio(1);
#pragma unroll
      for (int ks = 0; ks < 8; ++ks) {
        const bf16x8 af = *reinterpret_cast<const bf16x8*>(
            &mem_lds[arow * 256 + ((((ks << 2) + g) ^ (arow & 7)) << 3)]);
#pragma unroll
        for (int qt = 0; qt < 3; ++qt)
          sacc[qt] = __builtin_amdgcn_mfma_f32_16x16x32_bf16(af, bq[qt][ks], sacc[qt], 0, 0, 0);
      }
      __builtin_amdgcn_s_setprio(0);
    }

    // --- per-q max: in-lane 4, shfl over g, cross-wave via red_m[w][q] ---
#pragma unroll
    for (int qt = 0; qt < 3; ++qt) {
      float v = fmaxf(fmaxf(sacc[qt][0], sacc[qt][1]), fmaxf(sacc[qt][2], sacc[qt][3]));
      v = fmaxf(v, __shfl_xor(v, 16));
      v = fmaxf(v, __shfl_xor(v, 32));
      if (lane < 16) red_m[w * 48 + qt * 16 + lane] = v;
    }
    __syncthreads();   // (C) red_m ready

    float rfac[3], mnew[3];
#pragma unroll
    for (int qt = 0; qt < 3; ++qt) {
      const int q = qt * 16 + q16;
      const float tmax = fmaxf(fmaxf(red_m[q], red_m[48 + q]),
                               fmaxf(red_m[96 + q], red_m[144 + q]));
      mnew[qt] = fmaxf(m_run[qt], tmax);
      rfac[qt] = __expf(m_run[qt] - mnew[qt]);
      m_run[qt] = mnew[qt];
    }
    if (w == 0 && lane < 16) {
#pragma unroll
      for (int qt = 0; qt < 3; ++qt) r_lds[qt * 16 + lane] = rfac[qt];
    }

    // --- P = exp(S-m) -> p_lds bf16; partial sums -> red_l[w][q] ---
#pragma unroll
    for (int qt = 0; qt < 3; ++qt) {
      const float p0 = __expf(sacc[qt][0] - mnew[qt]);
      const float p1 = __expf(sacc[qt][1] - mnew[qt]);
      const float p2 = __expf(sacc[qt][2] - mnew[qt]);
      const float p3 = __expf(sacc[qt][3] - mnew[qt]);
      const int prow = (qt * 16 + q16) * PS3 + w * 16 + g * 4;
      *reinterpret_cast<unsigned*>(&p_lds[prow]) = cvtpk(p0, p1);
      *reinterpret_cast<unsigned*>(&p_lds[prow + 2]) = cvtpk(p2, p3);
      float ps = (p0 + p1) + (p2 + p3);
      ps += __shfl_xor(ps, 16);
      ps += __shfl_xor(ps, 32);
      if (lane < 16) red_l[w * 48 + qt * 16 + lane] = ps;
    }
    __syncthreads();   // (D) p_lds, red_l, r_lds ready

#pragma unroll
    for (int qt = 0; qt < 3; ++qt) {
      const int q = qt * 16 + q16;
      l_run[qt] = l_run[qt] * rfac[qt] +
                  ((red_l[q] + red_l[48 + q]) + (red_l[96 + q] + red_l[144 + q]));
    }
    // rescale ctx rows (row-mapped broadcast reads)
#pragma unroll
    for (int mt = 0; mt < 3; ++mt)
#pragma unroll
      for (int r = 0; r < 4; ++r) {
        const float rr = r_lds[mt * 16 + g * 4 + r];
#pragma unroll
        for (int nt = 0; nt < 4; ++nt) ctx[mt][nt][r] *= rr;
      }

    // --- PV: wave w owns c-slice [w*64, w*64+64) ---
    bf16x8 pf[3][2];
#pragma unroll
    for (int mt = 0; mt < 3; ++mt)
#pragma unroll
      for (int ks2 = 0; ks2 < 2; ++ks2)
        pf[mt][ks2] = *reinterpret_cast<const bf16x8*>(
            &p_lds[(mt * 16 + q16) * PS3 + ks2 * 32 + g * 8]);
    __builtin_amdgcn_s_setprio(1);
#pragma unroll
    for (int nt = 0; nt < 4; ++nt) {
      const int c = w * 64 + nt * 16 + q16;
#pragma unroll
      for (int ks2 = 0; ks2 < 2; ++ks2) {
        const bf16x8 bT = *reinterpret_cast<const bf16x8*>(
            &memT_lds[c * 64 + ((((ks2 << 2) + g) ^ (c & 7)) << 3)]);
#pragma unroll
        for (int mt = 0; mt < 3; ++mt)
          ctx[mt][nt] = __builtin_amdgcn_mfma_f32_16x16x32_bf16(pf[mt][ks2], bT,
                                                                ctx[mt][nt], 0, 0, 0);
      }
    }
    __builtin_amdgcn_s_setprio(0);
  }

  // --- write unnormalized o + (m,l) for this half ---
#pragma unroll
  for (int mt = 0; mt < 3; ++mt)
#pragma unroll
    for (int r = 0; r < 4; ++r) {
      const int q = mt * 16 + g * 4 + r;
      if (q < 34) {
        const size_t orow = (size_t)(half * ROWS + b * 34 + q) * 2048;
#pragma unroll
        for (int nt = 0; nt < 4; ++nt)
          o_part[orow + h * 256 + w * 64 + nt * 16 + q16] = ctx[mt][nt][r];
      }
    }
  if (w == 0 && lane < 16) {
#pragma unroll
    for (int qt = 0; qt < 3; ++qt) {
      const int q = qt * 16 + lane;
      if (q < 34) {
        const size_t idx = (size_t)(half * ROWS + b * 34 + q) * 8 + h;
        m_part[idx] = m_run[qt];
        l_part[idx] = l_run[qt];
      }
    }
  }
}

// ---------- combine the two T-halves -> ctx_bf ----------
__global__ __launch_bounds__(256) void ca_combine_kernel(
    const float* __restrict__ o_part, const float* __restrict__ m_part,
    const float* __restrict__ l_part, unsigned short* __restrict__ ctx_bf) {
  const int row = blockIdx.x, c = threadIdx.x;
#pragma unroll
  for (int h = 0; h < NHH; ++h) {
    const float m0 = m_part[(size_t)row * 8 + h];
    const float m1 = m_part[(size_t)(ROWS + row) * 8 + h];
    const float l0 = l_part[(size_t)row * 8 + h];
    const float l1 = l_part[(size_t)(ROWS + row) * 8 + h];
    const float M = fmaxf(m0, m1);
    const float w0 = __expf(m0 - M), w1 = __expf(m1 - M);
    const float denom = l0 * w0 + l1 * w1;
    const float o0 = o_part[(size_t)row * 2048 + h * 256 + c];
    const float o1 = o_part[(size_t)(ROWS + row) * 2048 + h * 256 + c];
    ctx_bf[(size_t)row * 2048 + h * 256 + c] = f2bf((o0 * w0 + o1 * w1) / denom);
  }
}

// ---------- refine pair-mean (fp32 in, bf16 out) ----------
__global__ __launch_bounds__(256) void pairmean_kernel(
    const float* __restrict__ u, const float* __restrict__ v,
    unsigned short* __restrict__ hbar_bf) {
  const int bp = blockIdx.x, tid = threadIdx.x;
  const int r0 = bp * KK;
  __shared__ float us[KK][132], vs[KK][132];
  for (int i = tid; i < KK * HIDD; i += 256) {
    const int r = i >> 7, f = i & 127;
    us[r][f] = u[(size_t)(r0 + r) * HIDD + f];
    vs[r][f] = v[(size_t)(r0 + r) * HIDD + f];
  }
  __syncthreads();
  for (int i = tid; i < KK * HIDD; i += 256) {
    const int r = i >> 7, f = i & 127;
    float s = 0.f;
#pragma unroll
    for (int j = 0; j < KK; ++j) s += fmaxf(us[r][f] + vs[j][f], 0.f);
    hbar_bf[(size_t)(r0 + r) * HIDD + f] = f2bf(s * (1.0f / 17.0f));
  }
}

static void gemm(const float* X, const float* W, const float* bias, const float* R,
                 float* Y, int M, int N, int K, int wstride, int relu, hipStream_t s) {
  dim3 g((N + 63) / 64, M / 64);
  gemm_kernel<<<g, 256, 0, s>>>(X, W, bias, R, Y, M, N, K, wstride, relu);
}
static void gemm_bf(const unsigned short* X, const unsigned short* W, const float* bias,
                    const float* R, float* Yf, unsigned short* Ybf, int M, int N, int K,
                    int wstride, int relu, hipStream_t s) {
  dim3 g(N / 64, M / 64);
  gemm_bf16_kernel<<<g, 256, 0, s>>>(X, W, bias, R, Yf, Ybf, M, N, K, wstride, relu);
}
static void gemm_ln(const unsigned short* X, const unsigned short* W, const float* bias,
                    const float* lnw, const float* lnb, float* xio, unsigned short* x_bf,
                    int K, int wstride, hipStream_t s) {
  gemm_bf16_ln_kernel<<<ROWS / 64, 256, 0, s>>>(X, W, bias, lnw, lnb, xio, x_bf, K, wstride);
}

extern "C" void kernel_launch(void* const* d_in, const int* in_sizes, int n_in,
                              void* d_out, int out_size, void* d_ws, size_t ws_size,
                              hipStream_t stream) {
  const float* memory   = (const float*)d_in[0];
  const float* person_q = (const float*)d_in[1];
  const float* key_q    = (const float*)d_in[2];
  const float* sa_in_w  = (const float*)d_in[3];
  const float* sa_in_b  = (const float*)d_in[4];
  const float* sa_out_w = (const float*)d_in[5];
  const float* sa_out_b = (const float*)d_in[6];
  const float* ca_in_w  = (const float*)d_in[7];
  const float* ca_in_b  = (const float*)d_in[8];
  const float* ca_out_w = (const float*)d_in[9];
  const float* ca_out_b = (const float*)d_in[10];
  const float* ff1_w = (const float*)d_in[11];
  const float* ff1_b = (const float*)d_in[12];
  const float* ff2_w = (const float*)d_in[13];
  const float* ff2_b = (const float*)d_in[14];
  const float* ln1_w = (const float*)d_in[15];
  const float* ln1_b = (const float*)d_in[16];
  const float* ln2_w = (const float*)d_in[17];
  const float* ln2_b = (const float*)d_in[18];
  const float* ln3_w = (const float*)d_in[19];
  const float* ln3_b = (const float*)d_in[20];
  const float* r1_w1 = (const float*)d_in[21];
  const float* r1_b1 = (const float*)d_in[22];
  const float* r1_w2 = (const float*)d_in[23];
  const float* r1_b2 = (const float*)d_in[24];
  const float* r2_w1 = (const float*)d_in[25];
  const float* r2_b1 = (const float*)d_in[26];
  const float* r2_w2 = (const float*)d_in[27];
  const float* r2_b2 = (const float*)d_in[28];
  const float* fc_w  = (const float*)d_in[29];
  const float* fc_b  = (const float*)d_in[30];
  float* out = (float*)d_out;

  char* wsb = (char*)d_ws;
  size_t off = 0;
  auto alloc = [&](size_t bytes) -> char* {
    char* p = wsb + off;
    off += (bytes + 255) & ~(size_t)255;
    return p;
  };
  float* x      = (float*)alloc((size_t)ROWS * DD * 4);
  float* qkv    = (float*)alloc((size_t)ROWS * 768 * 4);
  float* bvo    = (float*)alloc(3 * 256 * 4);
  float* bqk    = (float*)alloc((size_t)3 * 2048 * 4);
  float* ubuf   = (float*)alloc((size_t)ROWS * HIDD * 4);
  float* vbuf   = (float*)alloc((size_t)ROWS * HIDD * 4);
  float* o_part = (float*)alloc((size_t)2 * ROWS * 2048 * 4);
  float* m_part = (float*)alloc((size_t)2 * ROWS * 8 * 4);
  float* l_part = (float*)alloc((size_t)2 * ROWS * 8 * 4);
  unsigned short* x_bf     = (unsigned short*)alloc((size_t)ROWS * DD * 2);
  unsigned short* attn_bf  = (unsigned short*)alloc((size_t)ROWS * DD * 2);
  unsigned short* hff_bf   = (unsigned short*)alloc((size_t)ROWS * 2048 * 2);
  unsigned short* ctx_bf   = (unsigned short*)alloc((size_t)ROWS * 2048 * 2);
  unsigned short* qkeff_bf = (unsigned short*)alloc((size_t)ROWS * 2048 * 2);
  unsigned short* hbar_bf  = (unsigned short*)alloc((size_t)ROWS * HIDD * 2);
  unsigned short* mem_bf   = (unsigned short*)alloc((size_t)NB * TSEQ * DD * 2);
  unsigned short* memT     = (unsigned short*)alloc((size_t)NB * TSEQ * DD * 2);
  unsigned short* sa_in_bf  = (unsigned short*)alloc((size_t)3 * 768 * 256 * 2);
  unsigned short* sa_out_bf = (unsigned short*)alloc((size_t)3 * 256 * 256 * 2);
  unsigned short* Wqk_bf   = (unsigned short*)alloc((size_t)3 * 2048 * 256 * 2);
  unsigned short* ff1_bf   = (unsigned short*)alloc((size_t)3 * 2048 * 256 * 2);
  unsigned short* ff2_bf   = (unsigned short*)alloc((size_t)3 * 256 * 2048 * 2);
  unsigned short* Wvo_bf   = (unsigned short*)alloc((size_t)3 * 256 * 2048 * 2);
  unsigned short* r1w1_bf  = (unsigned short*)alloc((size_t)HIDD * 512 * 2);
  unsigned short* r1w2_bf  = (unsigned short*)alloc((size_t)DD * HIDD * 2);
  unsigned short* r2w1_bf  = (unsigned short*)alloc((size_t)HIDD * 512 * 2);
  unsigned short* r2w2_bf  = (unsigned short*)alloc((size_t)DD * HIDD * 2);

  // ---- prep ----
  prep_mem_kernel<<<NB * 64, 256, 0, stream>>>(memory, mem_bf, memT);
  CvtJobs8 jobs;
  jobs.j[0] = {sa_in_w,  sa_in_bf,  3 * 768 * 256};
  jobs.j[1] = {sa_out_w, sa_out_bf, 3 * 256 * 256};
  jobs.j[2] = {ff1_w,    ff1_bf,    3 * 2048 * 256};
  jobs.j[3] = {ff2_w,    ff2_bf,    3 * 256 * 2048};
  jobs.j[4] = {r1_w1,    r1w1_bf,   HIDD * 512};
  jobs.j[5] = {r1_w2,    r1w2_bf,   DD * HIDD};
  jobs.j[6] = {r2_w1,    r2w1_bf,   HIDD * 512};
  jobs.j[7] = {r2_w2,    r2w2_bf,   DD * HIDD};
  cvt_multi_kernel<<<1024, 256, 0, stream>>>(jobs);
  wqkvo_kernel<<<12288, 256, 0, stream>>>(ca_in_w, ca_out_w, Wqk_bf, Wvo_bf);
  prep_small_kernel<<<ROWS + 24 + 3, 256, 0, stream>>>(
      person_q, key_q, ca_in_w, ca_in_b, ca_out_w, ca_out_b, x, x_bf, bqk, bvo);

  for (int l = 0; l < LL; ++l) {
    // --- self-attention ---
    gemm_bf(x_bf, sa_in_bf + (size_t)l * 768 * 256, sa_in_b + l * 768, nullptr,
            qkv, nullptr, ROWS, 768, 256, 256, 0, stream);
    sa_attn_kernel<<<512, 64, 0, stream>>>(qkv, attn_bf);
    gemm_ln(attn_bf, sa_out_bf + (size_t)l * 256 * 256, sa_out_b + l * 256,
            ln1_w + l * 256, ln1_b + l * 256, x, x_bf, 256, 256, stream);
    // --- cross-attention: qk_eff = x @ Wqk^T + bqk (scale folded) ---
    gemm_bf(x_bf, Wqk_bf + (size_t)l * 2048 * 256, bqk + l * 2048, nullptr,
            nullptr, qkeff_bf, ROWS, 2048, 256, 256, 0, stream);
    ca_fused_kernel<<<512, 256, 0, stream>>>(qkeff_bf, mem_bf, memT, o_part, m_part, l_part);
    ca_combine_kernel<<<ROWS, 256, 0, stream>>>(o_part, m_part, l_part, ctx_bf);
    gemm_ln(ctx_bf, Wvo_bf + (size_t)l * 256 * 2048, bvo + l * 256,
            ln2_w + l * 256, ln2_b + l * 256, x, x_bf, 2048, 2048, stream);
    // --- feed-forward ---
    gemm_bf(x_bf, ff1_bf + (size_t)l * 2048 * 256, ff1_b + l * 2048, nullptr,
            nullptr, hff_bf, ROWS, 2048, 256, 256, 1, stream);
    gemm_ln(hff_bf, ff2_bf + (size_t)l * 256 * 2048, ff2_b + l * 256,
            ln3_w + l * 256, ln3_b + l * 256, x, x_bf, 2048, 2048, stream);
  }

  // --- two refine blocks (bf16 MFMA) ---
  const unsigned short* rw1_bf[2] = {r1w1_bf, r2w1_bf};
  const unsigned short* rw2_bf[2] = {r1w2_bf, r2w2_bf};
  const float* rb1[2] = {r1_b1, r2_b1};
  const float* rb2[2] = {r1_b2, r2_b2};
  for (int r = 0; r < 2; ++r) {
    gemm_bf(x_bf, rw1_bf[r], rb1[r], nullptr, ubuf, nullptr,
            ROWS, 128, 256, 512, 0, stream);
    gemm_bf(x_bf, rw1_bf[r] + 256, nullptr, nullptr, vbuf, nullptr,
            ROWS, 128, 256, 512, 0, stream);
    pairmean_kernel<<<64, 256, 0, stream>>>(ubuf, vbuf, hbar_bf);
    gemm_bf(hbar_bf, rw2_bf[r], rb2[r], x, x, x_bf,
            ROWS, 256, 128, 128, 0, stream);
  }

  // --- final fc (fp32, N=3 guarded) ---
  gemm(x, fc_w, fc_b, nullptr, out, ROWS, 3, 256, 256, 0, stream);
}

// Round 11
// 758.156 us; speedup vs baseline: 1.1835x; 1.1835x over previous
//
#include <hip/hip_runtime.h>
#include <stdint.h>

// Problem constants
#define NB   32
#define TSEQ 4096
#define DD   256
#define PP   2
#define KK   17
#define LL   3
#define NHH  8
#define HDD  32
#define FFD  2048
#define HIDD 128
#define ROWS 1088                    // B*P*K
#define SCALE 0.17677669529663689f   // 1/sqrt(32)

typedef __attribute__((ext_vector_type(4))) float f32x4;
typedef __attribute__((ext_vector_type(8))) short bf16x8;

static __device__ __forceinline__ unsigned cvtpk(float lo, float hi) {
  unsigned r;
  asm volatile("v_cvt_pk_bf16_f32 %0, %1, %2" : "=v"(r) : "v"(lo), "v"(hi));
  return r;
}
static __device__ __forceinline__ unsigned short f2bf(float f) {
  unsigned int x = __float_as_uint(f);
  return (unsigned short)((x + 0x7fffu + ((x >> 16) & 1u)) >> 16);
}
static __device__ __forceinline__ void gload_lds16(const void* g, void* l) {
  __builtin_amdgcn_global_load_lds(
      (const __attribute__((address_space(1))) unsigned int*)g,
      (__attribute__((address_space(3))) unsigned int*)l, 16, 0, 0);
}

// ---------- batched fp32 -> bf16 convert (8 jobs in one launch) ----------
struct CvtJob { const float* src; unsigned short* dst; int n; };
struct CvtJobs8 { CvtJob j[8]; };
__global__ __launch_bounds__(256) void cvt_multi_kernel(CvtJobs8 jobs) {
#pragma unroll
  for (int jj = 0; jj < 8; ++jj) {
    const float* src = jobs.j[jj].src;
    unsigned short* dst = jobs.j[jj].dst;
    const int n8 = jobs.j[jj].n >> 3;
    for (int i = blockIdx.x * 256 + threadIdx.x; i < n8; i += gridDim.x * 256) {
      const float4 f0 = *reinterpret_cast<const float4*>(src + i * 8);
      const float4 f1 = *reinterpret_cast<const float4*>(src + i * 8 + 4);
      uint4 st;
      st.x = cvtpk(f0.x, f0.y); st.y = cvtpk(f0.z, f0.w);
      st.z = cvtpk(f1.x, f1.y); st.w = cvtpk(f1.z, f1.w);
      *reinterpret_cast<uint4*>(dst + i * 8) = st;
    }
  }
}

// ---------- merged small prep: init_x (1088) + bqk (24) + bvo (3) ----------
__global__ __launch_bounds__(256) void prep_small_kernel(
    const float* __restrict__ person_q, const float* __restrict__ key_q,
    const float* __restrict__ ca_in_w, const float* __restrict__ ca_in_b,
    const float* __restrict__ ca_out_w, const float* __restrict__ ca_out_b,
    float* __restrict__ x, unsigned short* __restrict__ x_bf,
    float* __restrict__ bqk, float* __restrict__ bvo) {
  const int bx = blockIdx.x, tid = threadIdx.x;
  if (bx < ROWS) {
    const int p = (bx / KK) & 1, k = bx % KK;
    const float v = person_q[p * DD + tid] + key_q[k * DD + tid];
    x[(size_t)bx * DD + tid] = v;
    x_bf[(size_t)bx * DD + tid] = f2bf(v);
  } else if (bx < ROWS + 24) {
    const int b2 = bx - ROWS;
    const int l = b2 >> 3, h = b2 & 7;
    const float* Wk = ca_in_w + (size_t)l * 196608 + (size_t)(256 + h * 32) * 256;
    const float* bq = ca_in_b + l * 768 + h * 32;
    float acc = 0.f;
#pragma unroll
    for (int j = 0; j < 32; ++j) acc += bq[j] * Wk[(size_t)j * 256 + tid];
    bqk[(size_t)l * 2048 + h * 256 + tid] = acc * SCALE;
  } else {
    const int l = bx - ROWS - 24;
    float acc = ca_out_b[l * 256 + tid];
    for (int j = 0; j < 256; ++j)
      acc += ca_out_w[(size_t)l * 65536 + (size_t)tid * 256 + j] * ca_in_b[l * 768 + 512 + j];
    bvo[l * 256 + tid] = acc;
  }
}

// ---------- generic fp32 GEMM (final fc only) ----------
__global__ __launch_bounds__(256) void gemm_kernel(
    const float* __restrict__ X, const float* __restrict__ W,
    const float* __restrict__ bias, const float* __restrict__ R,
    float* __restrict__ Y, int M, int N, int K, int wstride, int relu) {
  __shared__ float As[16][68];
  __shared__ float Bs[16][68];
  const int tid = threadIdx.x;
  const int m0 = blockIdx.y * 64, n0 = blockIdx.x * 64;
  const int tr = tid >> 4, tc = tid & 15;
  const int lr = tid >> 2, lk = (tid & 3) << 2;
  float acc[4][4] = {{0.f, 0.f, 0.f, 0.f}, {0.f, 0.f, 0.f, 0.f},
                     {0.f, 0.f, 0.f, 0.f}, {0.f, 0.f, 0.f, 0.f}};
  for (int k0 = 0; k0 < K; k0 += 16) {
    const float4 av = *reinterpret_cast<const float4*>(&X[(size_t)(m0 + lr) * K + k0 + lk]);
    int wn = n0 + lr; if (wn >= N) wn = N - 1;
    const float4 bv = *reinterpret_cast<const float4*>(&W[(size_t)wn * wstride + k0 + lk]);
    __syncthreads();
    As[lk + 0][lr] = av.x; As[lk + 1][lr] = av.y; As[lk + 2][lr] = av.z; As[lk + 3][lr] = av.w;
    Bs[lk + 0][lr] = bv.x; Bs[lk + 1][lr] = bv.y; Bs[lk + 2][lr] = bv.z; Bs[lk + 3][lr] = bv.w;
    __syncthreads();
#pragma unroll
    for (int kk = 0; kk < 16; ++kk) {
      const float4 a = *reinterpret_cast<const float4*>(&As[kk][tr << 2]);
      const float4 b = *reinterpret_cast<const float4*>(&Bs[kk][tc << 2]);
      const float aa[4] = {a.x, a.y, a.z, a.w};
      const float bb[4] = {b.x, b.y, b.z, b.w};
#pragma unroll
      for (int r = 0; r < 4; ++r)
#pragma unroll
        for (int c = 0; c < 4; ++c) acc[r][c] += aa[r] * bb[c];
    }
  }
#pragma unroll
  for (int r = 0; r < 4; ++r) {
    const int m = m0 + (tr << 2) + r;
#pragma unroll
    for (int c = 0; c < 4; ++c) {
      const int n = n0 + (tc << 2) + c;
      if (n < N) {
        float o = acc[r][c];
        if (bias) o += bias[n];
        if (relu) o = fmaxf(o, 0.f);
        if (R) o += R[(size_t)m * N + n];
        Y[(size_t)m * N + n] = o;
      }
    }
  }
}

// ---------- bf16 MFMA GEMM: Y = act(Xbf @ Wbf^T + bias) [+ R] ----------
// M,N,K multiples of 64. 64x64 tile, 4 waves. (single-buffered: best measured)
__global__ __launch_bounds__(256) void gemm_bf16_kernel(
    const unsigned short* __restrict__ Xbf, const unsigned short* __restrict__ Wbf,
    const float* __restrict__ bias, const float* __restrict__ R,
    float* __restrict__ Yf, unsigned short* __restrict__ Ybf,
    int M, int N, int K, int wstride, int relu) {
  __shared__ unsigned short Xs[64 * 64];
  __shared__ unsigned short Ws[64 * 64];
  const int tid = threadIdx.x, lane = tid & 63, w = tid >> 6;
  const int g = lane >> 4, q16 = lane & 15;
  const int m0 = blockIdx.y * 64, n0 = blockIdx.x * 64;
  f32x4 acc[4];
#pragma unroll
  for (int nt = 0; nt < 4; ++nt) acc[nt] = (f32x4){0.f, 0.f, 0.f, 0.f};

  for (int k0 = 0; k0 < K; k0 += 64) {
    __syncthreads();
#pragma unroll
    for (int j = 0; j < 2; ++j) {
      const int cc = w * 2 + j;
      const int row = cc * 8 + (lane >> 3);
      const int sc = (lane & 7) ^ (row & 7);
      gload_lds16(Xbf + (size_t)(m0 + row) * K + k0 + sc * 8, &Xs[cc * 512]);
      gload_lds16(Wbf + (size_t)(n0 + row) * wstride + k0 + sc * 8, &Ws[cc * 512]);
    }
    asm volatile("s_waitcnt vmcnt(0)" ::: "memory");
    __syncthreads();
    const int arow = w * 16 + q16;
#pragma unroll
    for (int ks = 0; ks < 2; ++ks) {
      const bf16x8 a = *reinterpret_cast<const bf16x8*>(
          &Xs[arow * 64 + ((((ks << 2) + g) ^ (arow & 7)) << 3)]);
#pragma unroll
      for (int nt = 0; nt < 4; ++nt) {
        const int brow = nt * 16 + q16;
        const bf16x8 bfr = *reinterpret_cast<const bf16x8*>(
            &Ws[brow * 64 + ((((ks << 2) + g) ^ (brow & 7)) << 3)]);
        acc[nt] = __builtin_amdgcn_mfma_f32_16x16x32_bf16(a, bfr, acc[nt], 0, 0, 0);
      }
    }
  }
#pragma unroll
  for (int nt = 0; nt < 4; ++nt) {
    const int n = n0 + nt * 16 + q16;
    const float bv = bias ? bias[n] : 0.f;
#pragma unroll
    for (int r = 0; r < 4; ++r) {
      const int m = m0 + w * 16 + g * 4 + r;
      float o = acc[nt][r] + bv;
      if (relu) o = fmaxf(o, 0.f);
      if (R) o += R[(size_t)m * N + n];
      if (Yf) Yf[(size_t)m * N + n] = o;
      if (Ybf) Ybf[(size_t)m * N + n] = f2bf(o);
    }
  }
}

// ---------- self-attention over K=17 keypoints (bf16 out) ----------
__global__ __launch_bounds__(64) void sa_attn_kernel(
    const float* __restrict__ qkv, unsigned short* __restrict__ attn_bf) {
  const int blk = blockIdx.x;
  const int h = blk & 7, bp = blk >> 3;
  const int rowbase = bp * KK;
  const int tid = threadIdx.x;
  __shared__ float qs[KK][36], ks[KK][36], vs[KK][36];
  __shared__ float ss[KK][20];
  __shared__ float lsum[KK];
  for (int i = tid; i < KK * HDD; i += 64) {
    const int r = i >> 5, d = i & 31;
    const size_t base = (size_t)(rowbase + r) * 768 + h * 32 + d;
    qs[r][d] = qkv[base];
    ks[r][d] = qkv[base + 256];
    vs[r][d] = qkv[base + 512];
  }
  __syncthreads();
  for (int i = tid; i < KK * KK; i += 64) {
    const int q = i / KK, k = i % KK;
    float s = 0.f;
#pragma unroll
    for (int d = 0; d < HDD; ++d) s += qs[q][d] * ks[k][d];
    ss[q][k] = s * SCALE;
  }
  __syncthreads();
  if (tid < KK) {
    float m = -1e30f;
    for (int k = 0; k < KK; ++k) m = fmaxf(m, ss[tid][k]);
    float l = 0.f;
    for (int k = 0; k < KK; ++k) { const float e = __expf(ss[tid][k] - m); ss[tid][k] = e; l += e; }
    lsum[tid] = l;
  }
  __syncthreads();
  for (int i = tid; i < KK * HDD; i += 64) {
    const int q = i >> 5, d = i & 31;
    float o = 0.f;
#pragma unroll
    for (int k = 0; k < KK; ++k) o += ss[q][k] * vs[k][d];
    attn_bf[(size_t)(rowbase + q) * DD + h * 32 + d] = f2bf(o / lsum[q]);
  }
}

// ---------- merged Wqk + Wvo folding (grid 12288) ----------
__global__ __launch_bounds__(256) void wqkvo_kernel(
    const float* __restrict__ ca_in_w, const float* __restrict__ ca_out_w,
    unsigned short* __restrict__ Wqk_bf, unsigned short* __restrict__ Wvo_bf) {
  const int bx0 = blockIdx.x;
  if (bx0 < 6144) {
    const int l = bx0 >> 11, hc = bx0 & 2047;
    const int h = hc >> 8, c = hc & 255;
    const int d = threadIdx.x;
    const float* Wq = ca_in_w + (size_t)l * 196608 + (size_t)(h * 32) * 256;
    const float* Wk = ca_in_w + (size_t)l * 196608 + (size_t)(256 + h * 32) * 256;
    float acc = 0.f;
#pragma unroll
    for (int j = 0; j < 32; ++j) acc += Wk[(size_t)j * 256 + c] * Wq[(size_t)j * 256 + d];
    Wqk_bf[((size_t)l * 2048 + hc) * 256 + d] = f2bf(acc * SCALE);
  } else {
    const int bx = bx0 - 6144;
    const int h = bx & 7, dp = (bx >> 3) & 255, l = bx >> 11;
    const int c = threadIdx.x;
    const float* wout = ca_out_w + (size_t)l * 65536 + (size_t)dp * 256 + h * 32;
    const float* wv = ca_in_w + (size_t)l * 196608 + (size_t)(512 + h * 32) * 256 + c;
    float acc = 0.f;
#pragma unroll
    for (int j = 0; j < 32; ++j) acc += wout[j] * wv[(size_t)j * 256];
    Wvo_bf[((size_t)l * 256 + dp) * 2048 + h * 256 + c] = f2bf(acc);
  }
}

// ---------- prep: mem_bf[b][t][c] + memT[b][c][t] (both bf16) ----------
__global__ __launch_bounds__(256) void prep_mem_kernel(
    const float* __restrict__ memory, unsigned short* __restrict__ mem_bf,
    unsigned short* __restrict__ memT) {
  const int b = blockIdx.x >> 6, tc = blockIdx.x & 63;
  const int tid = threadIdx.x;
  __shared__ unsigned short tile[64][264];
  for (int it = 0; it < 8; ++it) {
    const int idx = it * 256 + tid;
    const int t = idx >> 5, c8 = (idx & 31) << 3;
    const size_t goff = ((size_t)b * TSEQ + tc * 64 + t) * DD + c8;
    const float4 f0 = *reinterpret_cast<const float4*>(memory + goff);
    const float4 f1 = *reinterpret_cast<const float4*>(memory + goff + 4);
    uint4 st;
    st.x = cvtpk(f0.x, f0.y); st.y = cvtpk(f0.z, f0.w);
    st.z = cvtpk(f1.x, f1.y); st.w = cvtpk(f1.z, f1.w);
    *reinterpret_cast<uint4*>(&tile[t][c8]) = st;
    *reinterpret_cast<uint4*>(mem_bf + goff) = st;
  }
  __syncthreads();
  for (int it = 0; it < 8; ++it) {
    const int idx = it * 256 + tid;
    const int c = idx >> 3, t8 = (idx & 7) << 3;
    union { unsigned short v[8]; uint4 u; } pk;
#pragma unroll
    for (int j = 0; j < 8; ++j) pk.v[j] = tile[t8 + j][c];
    *reinterpret_cast<uint4*>(&memT[((size_t)b * DD + c) * TSEQ + tc * 64 + t8]) = pk.u;
  }
}

// ---------- fused MFMA cross-attention flash (v4 — best measured: 130 µs) ----------
// grid 512: bid = h*64 + b*2 + half -> 8 heads of same (b,half) share bid%8 (XCD).
// 256 threads = 4 waves, t-tile 64, 32 tiles per block. LDS 74KB -> 2 blocks/CU.
#define PS3 72
__global__ __launch_bounds__(256, 2) void ca_fused_kernel(
    const unsigned short* __restrict__ qkeff_bf, const unsigned short* __restrict__ mem_bf,
    const unsigned short* __restrict__ memT,
    float* __restrict__ o_part, float* __restrict__ m_part, float* __restrict__ l_part) {
  const int h = blockIdx.x >> 6;
  const int b = (blockIdx.x >> 1) & 31;
  const int half = blockIdx.x & 1;
  const int tid = threadIdx.x;
  const int lane = tid & 63, w = tid >> 6;      // w in 0..3
  const int g = lane >> 4, q16 = lane & 15;

  __shared__ unsigned short mem_lds[64 * 256];    // [t][c], XOR-swizzled 16B chunks
  __shared__ unsigned short memT_lds[256 * 64];   // [c][t], XOR-swizzled 16B chunks
  __shared__ unsigned short p_lds[48 * PS3];
  __shared__ float red_m[4 * 48];                 // [w][q] transposed: conflict-free
  __shared__ float red_l[4 * 48];
  __shared__ float r_lds[48];

  // --- Q B-fragments direct bf16 (loop-invariant) ---
  bf16x8 bq[3][8];
#pragma unroll
  for (int qt = 0; qt < 3; ++qt) {
    const int ql = qt * 16 + q16;
    if (ql < 34) {
      const unsigned short* qbase = qkeff_bf + (size_t)(b * 34 + ql) * 2048 + h * 256;
#pragma unroll
      for (int ks = 0; ks < 8; ++ks)
        bq[qt][ks] = *reinterpret_cast<const bf16x8*>(qbase + ks * 32 + g * 8);
    } else {
#pragma unroll
      for (int ks = 0; ks < 8; ++ks) bq[qt][ks] = (bf16x8){0, 0, 0, 0, 0, 0, 0, 0};
    }
  }

  f32x4 ctx[3][4];
#pragma unroll
  for (int mt = 0; mt < 3; ++mt)
#pragma unroll
    for (int nt = 0; nt < 4; ++nt) ctx[mt][nt] = (f32x4){0.f, 0.f, 0.f, 0.f};
  float m_run[3] = {-1e30f, -1e30f, -1e30f};
  float l_run[3] = {0.f, 0.f, 0.f};

  const unsigned short* membb = mem_bf + (size_t)b * TSEQ * DD;
  const unsigned short* memTb = memT + (size_t)b * DD * TSEQ;

  for (int tile = 0; tile < 32; ++tile) {
    const int tbase = half * 2048 + tile * 64;
    __syncthreads();   // (A) previous tile fully consumed

    // --- stage mem tile 64x256 (32KB): 8 calls/wave, 1KB = 2 rows each ---
#pragma unroll
    for (int j = 0; j < 8; ++j) {
      const int cc = w * 8 + j;
      const int trow = cc * 2 + (lane >> 5);
      const int sc = (lane & 31) ^ (trow & 7);
      gload_lds16(membb + (size_t)(tbase + trow) * DD + sc * 8, &mem_lds[cc * 512]);
    }
    // --- stage memT tile 256x64 (32KB): 8 calls/wave, 1KB = 8 rows each ---
#pragma unroll
    for (int j = 0; j < 8; ++j) {
      const int cc = w * 8 + j;
      const int crow = cc * 8 + (lane >> 3);
      const int sc = (lane & 7) ^ (crow & 7);
      gload_lds16(memTb + (size_t)crow * TSEQ + tbase + sc * 8, &memT_lds[cc * 512]);
    }
    asm volatile("s_waitcnt vmcnt(0)" ::: "memory");
    __syncthreads();   // (B) staged

    // --- QK^T (swapped): wave w owns t-strip [w*16, w*16+16) ---
    f32x4 sacc[3];
#pragma unroll
    for (int qt = 0; qt < 3; ++qt) sacc[qt] = (f32x4){0.f, 0.f, 0.f, 0.f};
    {
      const int arow = w * 16 + q16;
      __builtin_amdgcn_s_setprio(1);
#pragma unroll
      for (int ks = 0; ks < 8; ++ks) {
        const bf16x8 af = *reinterpret_cast<const bf16x8*>(
            &mem_lds[arow * 256 + ((((ks << 2) + g) ^ (arow & 7)) << 3)]);
#pragma unroll
        for (int qt = 0; qt < 3; ++qt)
          sacc[qt] = __builtin_amdgcn_mfma_f32_16x16x32_bf16(af, bq[qt][ks], sacc[qt], 0, 0, 0);
      }
      __builtin_amdgcn_s_setprio(0);
    }

    // --- per-q max: in-lane 4, shfl over g, cross-wave via red_m[w][q] ---
#pragma unroll
    for (int qt = 0; qt < 3; ++qt) {
      float v = fmaxf(fmaxf(sacc[qt][0], sacc[qt][1]), fmaxf(sacc[qt][2], sacc[qt][3]));
      v = fmaxf(v, __shfl_xor(v, 16));
      v = fmaxf(v, __shfl_xor(v, 32));
      if (lane < 16) red_m[w * 48 + qt * 16 + lane] = v;
    }
    __syncthreads();   // (C) red_m ready

    float rfac[3], mnew[3];
#pragma unroll
    for (int qt = 0; qt < 3; ++qt) {
      const int q = qt * 16 + q16;
      const float tmax = fmaxf(fmaxf(red_m[q], red_m[48 + q]),
                               fmaxf(red_m[96 + q], red_m[144 + q]));
      mnew[qt] = fmaxf(m_run[qt], tmax);
      rfac[qt] = __expf(m_run[qt] - mnew[qt]);
      m_run[qt] = mnew[qt];
    }
    if (w == 0 && lane < 16) {
#pragma unroll
      for (int qt = 0; qt < 3; ++qt) r_lds[qt * 16 + lane] = rfac[qt];
    }

    // --- P = exp(S-m) -> p_lds bf16; partial sums -> red_l[w][q] ---
#pragma unroll
    for (int qt = 0; qt < 3; ++qt) {
      const float p0 = __expf(sacc[qt][0] - mnew[qt]);
      const float p1 = __expf(sacc[qt][1] - mnew[qt]);
      const float p2 = __expf(sacc[qt][2] - mnew[qt]);
      const float p3 = __expf(sacc[qt][3] - mnew[qt]);
      const int prow = (qt * 16 + q16) * PS3 + w * 16 + g * 4;
      *reinterpret_cast<unsigned*>(&p_lds[prow]) = cvtpk(p0, p1);
      *reinterpret_cast<unsigned*>(&p_lds[prow + 2]) = cvtpk(p2, p3);
      float ps = (p0 + p1) + (p2 + p3);
      ps += __shfl_xor(ps, 16);
      ps += __shfl_xor(ps, 32);
      if (lane < 16) red_l[w * 48 + qt * 16 + lane] = ps;
    }
    __syncthreads();   // (D) p_lds, red_l, r_lds ready

#pragma unroll
    for (int qt = 0; qt < 3; ++qt) {
      const int q = qt * 16 + q16;
      l_run[qt] = l_run[qt] * rfac[qt] +
                  ((red_l[q] + red_l[48 + q]) + (red_l[96 + q] + red_l[144 + q]));
    }
    // rescale ctx rows (row-mapped broadcast reads)
#pragma unroll
    for (int mt = 0; mt < 3; ++mt)
#pragma unroll
      for (int r = 0; r < 4; ++r) {
        const float rr = r_lds[mt * 16 + g * 4 + r];
#pragma unroll
        for (int nt = 0; nt < 4; ++nt) ctx[mt][nt][r] *= rr;
      }

    // --- PV: wave w owns c-slice [w*64, w*64+64) ---
    bf16x8 pf[3][2];
#pragma unroll
    for (int mt = 0; mt < 3; ++mt)
#pragma unroll
      for (int ks2 = 0; ks2 < 2; ++ks2)
        pf[mt][ks2] = *reinterpret_cast<const bf16x8*>(
            &p_lds[(mt * 16 + q16) * PS3 + ks2 * 32 + g * 8]);
    __builtin_amdgcn_s_setprio(1);
#pragma unroll
    for (int nt = 0; nt < 4; ++nt) {
      const int c = w * 64 + nt * 16 + q16;
#pragma unroll
      for (int ks2 = 0; ks2 < 2; ++ks2) {
        const bf16x8 bT = *reinterpret_cast<const bf16x8*>(
            &memT_lds[c * 64 + ((((ks2 << 2) + g) ^ (c & 7)) << 3)]);
#pragma unroll
        for (int mt = 0; mt < 3; ++mt)
          ctx[mt][nt] = __builtin_amdgcn_mfma_f32_16x16x32_bf16(pf[mt][ks2], bT,
                                                                ctx[mt][nt], 0, 0, 0);
      }
    }
    __builtin_amdgcn_s_setprio(0);
  }

  // --- write unnormalized o + (m,l) for this half ---
#pragma unroll
  for (int mt = 0; mt < 3; ++mt)
#pragma unroll
    for (int r = 0; r < 4; ++r) {
      const int q = mt * 16 + g * 4 + r;
      if (q < 34) {
        const size_t orow = (size_t)(half * ROWS + b * 34 + q) * 2048;
#pragma unroll
        for (int nt = 0; nt < 4; ++nt)
          o_part[orow + h * 256 + w * 64 + nt * 16 + q16] = ctx[mt][nt][r];
      }
    }
  if (w == 0 && lane < 16) {
#pragma unroll
    for (int qt = 0; qt < 3; ++qt) {
      const int q = qt * 16 + lane;
      if (q < 34) {
        const size_t idx = (size_t)(half * ROWS + b * 34 + q) * 8 + h;
        m_part[idx] = m_run[qt];
        l_part[idx] = l_run[qt];
      }
    }
  }
}

// ---------- combine the two T-halves -> ctx_bf ----------
__global__ __launch_bounds__(256) void ca_combine_kernel(
    const float* __restrict__ o_part, const float* __restrict__ m_part,
    const float* __restrict__ l_part, unsigned short* __restrict__ ctx_bf) {
  const int row = blockIdx.x, c = threadIdx.x;
#pragma unroll
  for (int h = 0; h < NHH; ++h) {
    const float m0 = m_part[(size_t)row * 8 + h];
    const float m1 = m_part[(size_t)(ROWS + row) * 8 + h];
    const float l0 = l_part[(size_t)row * 8 + h];
    const float l1 = l_part[(size_t)(ROWS + row) * 8 + h];
    const float M = fmaxf(m0, m1);
    const float w0 = __expf(m0 - M), w1 = __expf(m1 - M);
    const float denom = l0 * w0 + l1 * w1;
    const float o0 = o_part[(size_t)row * 2048 + h * 256 + c];
    const float o1 = o_part[(size_t)(ROWS + row) * 2048 + h * 256 + c];
    ctx_bf[(size_t)row * 2048 + h * 256 + c] = f2bf((o0 * w0 + o1 * w1) / denom);
  }
}

// ---------- residual + LayerNorm (fp32 + bf16 out) ----------
__global__ __launch_bounds__(256) void ln_kernel(
    const float* __restrict__ xin, const float* __restrict__ dlt,
    const float* __restrict__ w, const float* __restrict__ b,
    float* __restrict__ xout, unsigned short* __restrict__ xout_bf) {
  const int row = blockIdx.x, tid = threadIdx.x;
  const size_t base = (size_t)row * DD;
  const float v = xin[base + tid] + dlt[base + tid];
  float s = v, s2 = v * v;
#pragma unroll
  for (int off = 32; off > 0; off >>= 1) {
    s += __shfl_down(s, off);
    s2 += __shfl_down(s2, off);
  }
  __shared__ float ps[4], ps2[4];
  if ((tid & 63) == 0) { ps[tid >> 6] = s; ps2[tid >> 6] = s2; }
  __syncthreads();
  const float st = ps[0] + ps[1] + ps[2] + ps[3];
  const float st2 = ps2[0] + ps2[1] + ps2[2] + ps2[3];
  const float mean = st * (1.f / 256.f);
  const float var = st2 * (1.f / 256.f) - mean * mean;
  const float inv = rsqrtf(var + 1e-5f);
  const float o = (v - mean) * inv * w[tid] + b[tid];
  xout[base + tid] = o;
  xout_bf[base + tid] = f2bf(o);
}

// ---------- refine pair-mean (fp32 in, bf16 out) ----------
__global__ __launch_bounds__(256) void pairmean_kernel(
    const float* __restrict__ u, const float* __restrict__ v,
    unsigned short* __restrict__ hbar_bf) {
  const int bp = blockIdx.x, tid = threadIdx.x;
  const int r0 = bp * KK;
  __shared__ float us[KK][132], vs[KK][132];
  for (int i = tid; i < KK * HIDD; i += 256) {
    const int r = i >> 7, f = i & 127;
    us[r][f] = u[(size_t)(r0 + r) * HIDD + f];
    vs[r][f] = v[(size_t)(r0 + r) * HIDD + f];
  }
  __syncthreads();
  for (int i = tid; i < KK * HIDD; i += 256) {
    const int r = i >> 7, f = i & 127;
    float s = 0.f;
#pragma unroll
    for (int j = 0; j < KK; ++j) s += fmaxf(us[r][f] + vs[j][f], 0.f);
    hbar_bf[(size_t)(r0 + r) * HIDD + f] = f2bf(s * (1.0f / 17.0f));
  }
}

static void gemm(const float* X, const float* W, const float* bias, const float* R,
                 float* Y, int M, int N, int K, int wstride, int relu, hipStream_t s) {
  dim3 g((N + 63) / 64, M / 64);
  gemm_kernel<<<g, 256, 0, s>>>(X, W, bias, R, Y, M, N, K, wstride, relu);
}
static void gemm_bf(const unsigned short* X, const unsigned short* W, const float* bias,
                    const float* R, float* Yf, unsigned short* Ybf, int M, int N, int K,
                    int wstride, int relu, hipStream_t s) {
  dim3 g(N / 64, M / 64);
  gemm_bf16_kernel<<<g, 256, 0, s>>>(X, W, bias, R, Yf, Ybf, M, N, K, wstride, relu);
}

extern "C" void kernel_launch(void* const* d_in, const int* in_sizes, int n_in,
                              void* d_out, int out_size, void* d_ws, size_t ws_size,
                              hipStream_t stream) {
  const float* memory   = (const float*)d_in[0];
  const float* person_q = (const float*)d_in[1];
  const float* key_q    = (const float*)d_in[2];
  const float* sa_in_w  = (const float*)d_in[3];
  const float* sa_in_b  = (const float*)d_in[4];
  const float* sa_out_w = (const float*)d_in[5];
  const float* sa_out_b = (const float*)d_in[6];
  const float* ca_in_w  = (const float*)d_in[7];
  const float* ca_in_b  = (const float*)d_in[8];
  const float* ca_out_w = (const float*)d_in[9];
  const float* ca_out_b = (const float*)d_in[10];
  const float* ff1_w = (const float*)d_in[11];
  const float* ff1_b = (const float*)d_in[12];
  const float* ff2_w = (const float*)d_in[13];
  const float* ff2_b = (const float*)d_in[14];
  const float* ln1_w = (const float*)d_in[15];
  const float* ln1_b = (const float*)d_in[16];
  const float* ln2_w = (const float*)d_in[17];
  const float* ln2_b = (const float*)d_in[18];
  const float* ln3_w = (const float*)d_in[19];
  const float* ln3_b = (const float*)d_in[20];
  const float* r1_w1 = (const float*)d_in[21];
  const float* r1_b1 = (const float*)d_in[22];
  const float* r1_w2 = (const float*)d_in[23];
  const float* r1_b2 = (const float*)d_in[24];
  const float* r2_w1 = (const float*)d_in[25];
  const float* r2_b1 = (const float*)d_in[26];
  const float* r2_w2 = (const float*)d_in[27];
  const float* r2_b2 = (const float*)d_in[28];
  const float* fc_w  = (const float*)d_in[29];
  const float* fc_b  = (const float*)d_in[30];
  float* out = (float*)d_out;

  char* wsb = (char*)d_ws;
  size_t off = 0;
  auto alloc = [&](size_t bytes) -> char* {
    char* p = wsb + off;
    off += (bytes + 255) & ~(size_t)255;
    return p;
  };
  float* x      = (float*)alloc((size_t)ROWS * DD * 4);
  float* qkv    = (float*)alloc((size_t)ROWS * 768 * 4);
  float* delta  = (float*)alloc((size_t)ROWS * DD * 4);
  float* bvo    = (float*)alloc(3 * 256 * 4);
  float* bqk    = (float*)alloc((size_t)3 * 2048 * 4);
  float* ubuf   = (float*)alloc((size_t)ROWS * HIDD * 4);
  float* vbuf   = (float*)alloc((size_t)ROWS * HIDD * 4);
  float* o_part = (float*)alloc((size_t)2 * ROWS * 2048 * 4);
  float* m_part = (float*)alloc((size_t)2 * ROWS * 8 * 4);
  float* l_part = (float*)alloc((size_t)2 * ROWS * 8 * 4);
  unsigned short* x_bf     = (unsigned short*)alloc((size_t)ROWS * DD * 2);
  unsigned short* attn_bf  = (unsigned short*)alloc((size_t)ROWS * DD * 2);
  unsigned short* hff_bf   = (unsigned short*)alloc((size_t)ROWS * 2048 * 2);
  unsigned short* ctx_bf   = (unsigned short*)alloc((size_t)ROWS * 2048 * 2);
  unsigned short* qkeff_bf = (unsigned short*)alloc((size_t)ROWS * 2048 * 2);
  unsigned short* hbar_bf  = (unsigned short*)alloc((size_t)ROWS * HIDD * 2);
  unsigned short* mem_bf   = (unsigned short*)alloc((size_t)NB * TSEQ * DD * 2);
  unsigned short* memT     = (unsigned short*)alloc((size_t)NB * TSEQ * DD * 2);
  unsigned short* sa_in_bf  = (unsigned short*)alloc((size_t)3 * 768 * 256 * 2);
  unsigned short* sa_out_bf = (unsigned short*)alloc((size_t)3 * 256 * 256 * 2);
  unsigned short* Wqk_bf   = (unsigned short*)alloc((size_t)3 * 2048 * 256 * 2);
  unsigned short* ff1_bf   = (unsigned short*)alloc((size_t)3 * 2048 * 256 * 2);
  unsigned short* ff2_bf   = (unsigned short*)alloc((size_t)3 * 256 * 2048 * 2);
  unsigned short* Wvo_bf   = (unsigned short*)alloc((size_t)3 * 256 * 2048 * 2);
  unsigned short* r1w1_bf  = (unsigned short*)alloc((size_t)HIDD * 512 * 2);
  unsigned short* r1w2_bf  = (unsigned short*)alloc((size_t)DD * HIDD * 2);
  unsigned short* r2w1_bf  = (unsigned short*)alloc((size_t)HIDD * 512 * 2);
  unsigned short* r2w2_bf  = (unsigned short*)alloc((size_t)DD * HIDD * 2);

  // ---- prep ----
  prep_mem_kernel<<<NB * 64, 256, 0, stream>>>(memory, mem_bf, memT);
  CvtJobs8 jobs;
  jobs.j[0] = {sa_in_w,  sa_in_bf,  3 * 768 * 256};
  jobs.j[1] = {sa_out_w, sa_out_bf, 3 * 256 * 256};
  jobs.j[2] = {ff1_w,    ff1_bf,    3 * 2048 * 256};
  jobs.j[3] = {ff2_w,    ff2_bf,    3 * 256 * 2048};
  jobs.j[4] = {r1_w1,    r1w1_bf,   HIDD * 512};
  jobs.j[5] = {r1_w2,    r1w2_bf,   DD * HIDD};
  jobs.j[6] = {r2_w1,    r2w1_bf,   HIDD * 512};
  jobs.j[7] = {r2_w2,    r2w2_bf,   DD * HIDD};
  cvt_multi_kernel<<<1024, 256, 0, stream>>>(jobs);
  wqkvo_kernel<<<12288, 256, 0, stream>>>(ca_in_w, ca_out_w, Wqk_bf, Wvo_bf);
  prep_small_kernel<<<ROWS + 24 + 3, 256, 0, stream>>>(
      person_q, key_q, ca_in_w, ca_in_b, ca_out_w, ca_out_b, x, x_bf, bqk, bvo);

  for (int l = 0; l < LL; ++l) {
    // --- self-attention ---
    gemm_bf(x_bf, sa_in_bf + (size_t)l * 768 * 256, sa_in_b + l * 768, nullptr,
            qkv, nullptr, ROWS, 768, 256, 256, 0, stream);
    sa_attn_kernel<<<512, 64, 0, stream>>>(qkv, attn_bf);
    gemm_bf(attn_bf, sa_out_bf + (size_t)l * 256 * 256, sa_out_b + l * 256, nullptr,
            delta, nullptr, ROWS, 256, 256, 256, 0, stream);
    ln_kernel<<<ROWS, 256, 0, stream>>>(x, delta, ln1_w + l * 256, ln1_b + l * 256, x, x_bf);
    // --- cross-attention: qk_eff = x @ Wqk^T + bqk (scale folded) ---
    gemm_bf(x_bf, Wqk_bf + (size_t)l * 2048 * 256, bqk + l * 2048, nullptr,
            nullptr, qkeff_bf, ROWS, 2048, 256, 256, 0, stream);
    ca_fused_kernel<<<512, 256, 0, stream>>>(qkeff_bf, mem_bf, memT, o_part, m_part, l_part);
    ca_combine_kernel<<<ROWS, 256, 0, stream>>>(o_part, m_part, l_part, ctx_bf);
    gemm_bf(ctx_bf, Wvo_bf + (size_t)l * 256 * 2048, bvo + l * 256, nullptr,
            delta, nullptr, ROWS, 256, 2048, 2048, 0, stream);
    ln_kernel<<<ROWS, 256, 0, stream>>>(x, delta, ln2_w + l * 256, ln2_b + l * 256, x, x_bf);
    // --- feed-forward ---
    gemm_bf(x_bf, ff1_bf + (size_t)l * 2048 * 256, ff1_b + l * 2048, nullptr,
            nullptr, hff_bf, ROWS, 2048, 256, 256, 1, stream);
    gemm_bf(hff_bf, ff2_bf + (size_t)l * 256 * 2048, ff2_b + l * 256, nullptr,
            delta, nullptr, ROWS, 256, 2048, 2048, 0, stream);
    ln_kernel<<<ROWS, 256, 0, stream>>>(x, delta, ln3_w + l * 256, ln3_b + l * 256, x, x_bf);
  }

  // --- two refine blocks (bf16 MFMA) ---
  const unsigned short* rw1_bf[2] = {r1w1_bf, r2w1_bf};
  const unsigned short* rw2_bf[2] = {r1w2_bf, r2w2_bf};
  const float* rb1[2] = {r1_b1, r2_b1};
  const float* rb2[2] = {r1_b2, r2_b2};
  for (int r = 0; r < 2; ++r) {
    gemm_bf(x_bf, rw1_bf[r], rb1[r], nullptr, ubuf, nullptr,
            ROWS, 128, 256, 512, 0, stream);
    gemm_bf(x_bf, rw1_bf[r] + 256, nullptr, nullptr, vbuf, nullptr,
            ROWS, 128, 256, 512, 0, stream);
    pairmean_kernel<<<64, 256, 0, stream>>>(ubuf, vbuf, hbar_bf);
    gemm_bf(hbar_bf, rw2_bf[r], rb2[r], x, x, x_bf,
            ROWS, 256, 128, 128, 0, stream);
  }

  // --- final fc (fp32, N=3 guarded) ---
  gemm(x, fc_w, fc_b, nullptr, out, ROWS, 3, 256, 256, 0, stream);
}

// Round 12
// 662.809 us; speedup vs baseline: 1.3537x; 1.1439x over previous
//
#include <hip/hip_runtime.h>
#include <stdint.h>

// Problem constants
#define NB   32
#define TSEQ 4096
#define DD   256
#define PP   2
#define KK   17
#define LL   3
#define NHH  8
#define HDD  32
#define FFD  2048
#define HIDD 128
#define ROWS 1088                    // B*P*K
#define SCALE 0.17677669529663689f   // 1/sqrt(32)

typedef __attribute__((ext_vector_type(4))) float f32x4;
typedef __attribute__((ext_vector_type(8))) short bf16x8;

static __device__ __forceinline__ unsigned cvtpk(float lo, float hi) {
  unsigned r;
  asm volatile("v_cvt_pk_bf16_f32 %0, %1, %2" : "=v"(r) : "v"(lo), "v"(hi));
  return r;
}
static __device__ __forceinline__ unsigned short f2bf(float f) {
  unsigned int x = __float_as_uint(f);
  return (unsigned short)((x + 0x7fffu + ((x >> 16) & 1u)) >> 16);
}
static __device__ __forceinline__ void gload_lds16(const void* g, void* l) {
  __builtin_amdgcn_global_load_lds(
      (const __attribute__((address_space(1))) unsigned int*)g,
      (__attribute__((address_space(3))) unsigned int*)l, 16, 0, 0);
}

// ---------- batched fp32 -> bf16 convert (8 jobs in one launch) ----------
struct CvtJob { const float* src; unsigned short* dst; int n; };
struct CvtJobs8 { CvtJob j[8]; };
__global__ __launch_bounds__(256) void cvt_multi_kernel(CvtJobs8 jobs) {
#pragma unroll
  for (int jj = 0; jj < 8; ++jj) {
    const float* src = jobs.j[jj].src;
    unsigned short* dst = jobs.j[jj].dst;
    const int n8 = jobs.j[jj].n >> 3;
    for (int i = blockIdx.x * 256 + threadIdx.x; i < n8; i += gridDim.x * 256) {
      const float4 f0 = *reinterpret_cast<const float4*>(src + i * 8);
      const float4 f1 = *reinterpret_cast<const float4*>(src + i * 8 + 4);
      uint4 st;
      st.x = cvtpk(f0.x, f0.y); st.y = cvtpk(f0.z, f0.w);
      st.z = cvtpk(f1.x, f1.y); st.w = cvtpk(f1.z, f1.w);
      *reinterpret_cast<uint4*>(dst + i * 8) = st;
    }
  }
}

// ---------- merged small prep: init_x (1088) + bqk (24) + bvo (3) ----------
__global__ __launch_bounds__(256) void prep_small_kernel(
    const float* __restrict__ person_q, const float* __restrict__ key_q,
    const float* __restrict__ ca_in_w, const float* __restrict__ ca_in_b,
    const float* __restrict__ ca_out_w, const float* __restrict__ ca_out_b,
    float* __restrict__ x, unsigned short* __restrict__ x_bf,
    float* __restrict__ bqk, float* __restrict__ bvo) {
  const int bx = blockIdx.x, tid = threadIdx.x;
  if (bx < ROWS) {
    const int p = (bx / KK) & 1, k = bx % KK;
    const float v = person_q[p * DD + tid] + key_q[k * DD + tid];
    x[(size_t)bx * DD + tid] = v;
    x_bf[(size_t)bx * DD + tid] = f2bf(v);
  } else if (bx < ROWS + 24) {
    const int b2 = bx - ROWS;
    const int l = b2 >> 3, h = b2 & 7;
    const float* Wk = ca_in_w + (size_t)l * 196608 + (size_t)(256 + h * 32) * 256;
    const float* bq = ca_in_b + l * 768 + h * 32;
    float acc = 0.f;
#pragma unroll
    for (int j = 0; j < 32; ++j) acc += bq[j] * Wk[(size_t)j * 256 + tid];
    bqk[(size_t)l * 2048 + h * 256 + tid] = acc * SCALE;
  } else {
    const int l = bx - ROWS - 24;
    float acc = ca_out_b[l * 256 + tid];
    for (int j = 0; j < 256; ++j)
      acc += ca_out_w[(size_t)l * 65536 + (size_t)tid * 256 + j] * ca_in_b[l * 768 + 512 + j];
    bvo[l * 256 + tid] = acc;
  }
}

// ---------- bf16 MFMA GEMM: Y = act(Xbf @ Wbf^T + bias) [+ R] ----------
// M,N,K multiples of 64. 64x64 tile, 4 waves. (single-buffered: best measured)
__global__ __launch_bounds__(256) void gemm_bf16_kernel(
    const unsigned short* __restrict__ Xbf, const unsigned short* __restrict__ Wbf,
    const float* __restrict__ bias, const float* __restrict__ R,
    float* __restrict__ Yf, unsigned short* __restrict__ Ybf,
    int M, int N, int K, int wstride, int relu) {
  __shared__ unsigned short Xs[64 * 64];
  __shared__ unsigned short Ws[64 * 64];
  const int tid = threadIdx.x, lane = tid & 63, w = tid >> 6;
  const int g = lane >> 4, q16 = lane & 15;
  const int m0 = blockIdx.y * 64, n0 = blockIdx.x * 64;
  f32x4 acc[4];
#pragma unroll
  for (int nt = 0; nt < 4; ++nt) acc[nt] = (f32x4){0.f, 0.f, 0.f, 0.f};

  for (int k0 = 0; k0 < K; k0 += 64) {
    __syncthreads();
#pragma unroll
    for (int j = 0; j < 2; ++j) {
      const int cc = w * 2 + j;
      const int row = cc * 8 + (lane >> 3);
      const int sc = (lane & 7) ^ (row & 7);
      gload_lds16(Xbf + (size_t)(m0 + row) * K + k0 + sc * 8, &Xs[cc * 512]);
      gload_lds16(Wbf + (size_t)(n0 + row) * wstride + k0 + sc * 8, &Ws[cc * 512]);
    }
    asm volatile("s_waitcnt vmcnt(0)" ::: "memory");
    __syncthreads();
    const int arow = w * 16 + q16;
#pragma unroll
    for (int ks = 0; ks < 2; ++ks) {
      const bf16x8 a = *reinterpret_cast<const bf16x8*>(
          &Xs[arow * 64 + ((((ks << 2) + g) ^ (arow & 7)) << 3)]);
#pragma unroll
      for (int nt = 0; nt < 4; ++nt) {
        const int brow = nt * 16 + q16;
        const bf16x8 bfr = *reinterpret_cast<const bf16x8*>(
            &Ws[brow * 64 + ((((ks << 2) + g) ^ (brow & 7)) << 3)]);
        acc[nt] = __builtin_amdgcn_mfma_f32_16x16x32_bf16(a, bfr, acc[nt], 0, 0, 0);
      }
    }
  }
#pragma unroll
  for (int nt = 0; nt < 4; ++nt) {
    const int n = n0 + nt * 16 + q16;
    const float bv = bias ? bias[n] : 0.f;
#pragma unroll
    for (int r = 0; r < 4; ++r) {
      const int m = m0 + w * 16 + g * 4 + r;
      float o = acc[nt][r] + bv;
      if (relu) o = fmaxf(o, 0.f);
      if (R) o += R[(size_t)m * N + n];
      if (Yf) Yf[(size_t)m * N + n] = o;
      if (Ybf) Ybf[(size_t)m * N + n] = f2bf(o);
    }
  }
}

// ---------- split-K bf16 MFMA GEMM: part[kz] = Xbf[:,kz*ksl:(kz+1)*ksl] @ W^T ----------
// Same tile/dataflow as gemm_bf16; no bias/relu; fp32 partials.
__global__ __launch_bounds__(256) void gemm_bf16_sk_kernel(
    const unsigned short* __restrict__ Xbf, const unsigned short* __restrict__ Wbf,
    float* __restrict__ part, int M, int N, int K, int wstride, int kslice) {
  __shared__ unsigned short Xs[64 * 64];
  __shared__ unsigned short Ws[64 * 64];
  const int tid = threadIdx.x, lane = tid & 63, w = tid >> 6;
  const int g = lane >> 4, q16 = lane & 15;
  const int m0 = blockIdx.y * 64, n0 = blockIdx.x * 64;
  const int kz = blockIdx.z;
  const int kbeg = kz * kslice, kend = kbeg + kslice;
  f32x4 acc[4];
#pragma unroll
  for (int nt = 0; nt < 4; ++nt) acc[nt] = (f32x4){0.f, 0.f, 0.f, 0.f};

  for (int k0 = kbeg; k0 < kend; k0 += 64) {
    __syncthreads();
#pragma unroll
    for (int j = 0; j < 2; ++j) {
      const int cc = w * 2 + j;
      const int row = cc * 8 + (lane >> 3);
      const int sc = (lane & 7) ^ (row & 7);
      gload_lds16(Xbf + (size_t)(m0 + row) * K + k0 + sc * 8, &Xs[cc * 512]);
      gload_lds16(Wbf + (size_t)(n0 + row) * wstride + k0 + sc * 8, &Ws[cc * 512]);
    }
    asm volatile("s_waitcnt vmcnt(0)" ::: "memory");
    __syncthreads();
    const int arow = w * 16 + q16;
#pragma unroll
    for (int ks = 0; ks < 2; ++ks) {
      const bf16x8 a = *reinterpret_cast<const bf16x8*>(
          &Xs[arow * 64 + ((((ks << 2) + g) ^ (arow & 7)) << 3)]);
#pragma unroll
      for (int nt = 0; nt < 4; ++nt) {
        const int brow = nt * 16 + q16;
        const bf16x8 bfr = *reinterpret_cast<const bf16x8*>(
            &Ws[brow * 64 + ((((ks << 2) + g) ^ (brow & 7)) << 3)]);
        acc[nt] = __builtin_amdgcn_mfma_f32_16x16x32_bf16(a, bfr, acc[nt], 0, 0, 0);
      }
    }
  }
  float* pout = part + (size_t)kz * M * N;
#pragma unroll
  for (int nt = 0; nt < 4; ++nt) {
    const int n = n0 + nt * 16 + q16;
#pragma unroll
    for (int r = 0; r < 4; ++r) {
      const int m = m0 + w * 16 + g * 4 + r;
      pout[(size_t)m * N + n] = acc[nt][r];
    }
  }
}

// ---------- reduce split-K partials + bias + residual + LayerNorm ----------
// x <- LN(x + bias + sum_{p<np} parts[p]); fp32 + bf16 out. grid ROWS.
__global__ __launch_bounds__(256) void ln_red_kernel(
    const float* __restrict__ xin, const float* __restrict__ parts, int np,
    const float* __restrict__ bias, const float* __restrict__ w,
    const float* __restrict__ b, float* __restrict__ xout,
    unsigned short* __restrict__ xout_bf) {
  const int row = blockIdx.x, tid = threadIdx.x;
  const size_t base = (size_t)row * DD + tid;
  float v = xin[base] + bias[tid];
  for (int p = 0; p < np; ++p) v += parts[(size_t)p * ROWS * DD + base];
  float s = v, s2 = v * v;
#pragma unroll
  for (int off = 32; off > 0; off >>= 1) {
    s += __shfl_down(s, off);
    s2 += __shfl_down(s2, off);
  }
  __shared__ float ps[4], ps2[4];
  if ((tid & 63) == 0) { ps[tid >> 6] = s; ps2[tid >> 6] = s2; }
  __syncthreads();
  const float st = ps[0] + ps[1] + ps[2] + ps[3];
  const float st2 = ps2[0] + ps2[1] + ps2[2] + ps2[3];
  const float mean = st * (1.f / 256.f);
  const float var = st2 * (1.f / 256.f) - mean * mean;
  const float inv = rsqrtf(var + 1e-5f);
  const float o = (v - mean) * inv * w[tid] + b[tid];
  xout[base] = o;
  xout_bf[base] = f2bf(o);
}

// ---------- final fc: out[m][0..2] = x[m] . fc_w[o] + fc_b[o] ----------
// one wave per row; grid ROWS/4, 256 threads.
__global__ __launch_bounds__(256) void fc_kernel(
    const float* __restrict__ x, const float* __restrict__ fc_w,
    const float* __restrict__ fc_b, float* __restrict__ out) {
  const int row = blockIdx.x * 4 + (threadIdx.x >> 6);
  const int lane = threadIdx.x & 63;
  float xr[4];
#pragma unroll
  for (int j = 0; j < 4; ++j) xr[j] = x[(size_t)row * DD + lane + 64 * j];
#pragma unroll
  for (int o = 0; o < 3; ++o) {
    float s = 0.f;
#pragma unroll
    for (int j = 0; j < 4; ++j) s += xr[j] * fc_w[o * DD + lane + 64 * j];
#pragma unroll
    for (int off = 32; off > 0; off >>= 1) s += __shfl_down(s, off);
    if (lane == 0) out[(size_t)row * 3 + o] = s + fc_b[o];
  }
}

// ---------- self-attention over K=17 keypoints (bf16 out) ----------
__global__ __launch_bounds__(64) void sa_attn_kernel(
    const float* __restrict__ qkv, unsigned short* __restrict__ attn_bf) {
  const int blk = blockIdx.x;
  const int h = blk & 7, bp = blk >> 3;
  const int rowbase = bp * KK;
  const int tid = threadIdx.x;
  __shared__ float qs[KK][36], ks[KK][36], vs[KK][36];
  __shared__ float ss[KK][20];
  __shared__ float lsum[KK];
  for (int i = tid; i < KK * HDD; i += 64) {
    const int r = i >> 5, d = i & 31;
    const size_t base = (size_t)(rowbase + r) * 768 + h * 32 + d;
    qs[r][d] = qkv[base];
    ks[r][d] = qkv[base + 256];
    vs[r][d] = qkv[base + 512];
  }
  __syncthreads();
  for (int i = tid; i < KK * KK; i += 64) {
    const int q = i / KK, k = i % KK;
    float s = 0.f;
#pragma unroll
    for (int d = 0; d < HDD; ++d) s += qs[q][d] * ks[k][d];
    ss[q][k] = s * SCALE;
  }
  __syncthreads();
  if (tid < KK) {
    float m = -1e30f;
    for (int k = 0; k < KK; ++k) m = fmaxf(m, ss[tid][k]);
    float l = 0.f;
    for (int k = 0; k < KK; ++k) { const float e = __expf(ss[tid][k] - m); ss[tid][k] = e; l += e; }
    lsum[tid] = l;
  }
  __syncthreads();
  for (int i = tid; i < KK * HDD; i += 64) {
    const int q = i >> 5, d = i & 31;
    float o = 0.f;
#pragma unroll
    for (int k = 0; k < KK; ++k) o += ss[q][k] * vs[k][d];
    attn_bf[(size_t)(rowbase + q) * DD + h * 32 + d] = f2bf(o / lsum[q]);
  }
}

// ---------- merged Wqk + Wvo folding (grid 12288) ----------
__global__ __launch_bounds__(256) void wqkvo_kernel(
    const float* __restrict__ ca_in_w, const float* __restrict__ ca_out_w,
    unsigned short* __restrict__ Wqk_bf, unsigned short* __restrict__ Wvo_bf) {
  const int bx0 = blockIdx.x;
  if (bx0 < 6144) {
    const int l = bx0 >> 11, hc = bx0 & 2047;
    const int h = hc >> 8, c = hc & 255;
    const int d = threadIdx.x;
    const float* Wq = ca_in_w + (size_t)l * 196608 + (size_t)(h * 32) * 256;
    const float* Wk = ca_in_w + (size_t)l * 196608 + (size_t)(256 + h * 32) * 256;
    float acc = 0.f;
#pragma unroll
    for (int j = 0; j < 32; ++j) acc += Wk[(size_t)j * 256 + c] * Wq[(size_t)j * 256 + d];
    Wqk_bf[((size_t)l * 2048 + hc) * 256 + d] = f2bf(acc * SCALE);
  } else {
    const int bx = bx0 - 6144;
    const int h = bx & 7, dp = (bx >> 3) & 255, l = bx >> 11;
    const int c = threadIdx.x;
    const float* wout = ca_out_w + (size_t)l * 65536 + (size_t)dp * 256 + h * 32;
    const float* wv = ca_in_w + (size_t)l * 196608 + (size_t)(512 + h * 32) * 256 + c;
    float acc = 0.f;
#pragma unroll
    for (int j = 0; j < 32; ++j) acc += wout[j] * wv[(size_t)j * 256];
    Wvo_bf[((size_t)l * 256 + dp) * 2048 + h * 256 + c] = f2bf(acc);
  }
}

// ---------- prep: mem_bf[b][t][c] + memT[b][c][t] (both bf16) ----------
__global__ __launch_bounds__(256) void prep_mem_kernel(
    const float* __restrict__ memory, unsigned short* __restrict__ mem_bf,
    unsigned short* __restrict__ memT) {
  const int b = blockIdx.x >> 6, tc = blockIdx.x & 63;
  const int tid = threadIdx.x;
  __shared__ unsigned short tile[64][264];
  for (int it = 0; it < 8; ++it) {
    const int idx = it * 256 + tid;
    const int t = idx >> 5, c8 = (idx & 31) << 3;
    const size_t goff = ((size_t)b * TSEQ + tc * 64 + t) * DD + c8;
    const float4 f0 = *reinterpret_cast<const float4*>(memory + goff);
    const float4 f1 = *reinterpret_cast<const float4*>(memory + goff + 4);
    uint4 st;
    st.x = cvtpk(f0.x, f0.y); st.y = cvtpk(f0.z, f0.w);
    st.z = cvtpk(f1.x, f1.y); st.w = cvtpk(f1.z, f1.w);
    *reinterpret_cast<uint4*>(&tile[t][c8]) = st;
    *reinterpret_cast<uint4*>(mem_bf + goff) = st;
  }
  __syncthreads();
  for (int it = 0; it < 8; ++it) {
    const int idx = it * 256 + tid;
    const int c = idx >> 3, t8 = (idx & 7) << 3;
    union { unsigned short v[8]; uint4 u; } pk;
#pragma unroll
    for (int j = 0; j < 8; ++j) pk.v[j] = tile[t8 + j][c];
    *reinterpret_cast<uint4*>(&memT[((size_t)b * DD + c) * TSEQ + tc * 64 + t8]) = pk.u;
  }
}

// ---------- fused MFMA cross-attention flash (v4 — best measured) ----------
// grid 512: bid = h*64 + b*2 + half -> 8 heads of same (b,half) share bid%8 (XCD).
// 256 threads = 4 waves, t-tile 64, 32 tiles per block. LDS 74KB -> 2 blocks/CU.
#define PS3 72
__global__ __launch_bounds__(256, 2) void ca_fused_kernel(
    const unsigned short* __restrict__ qkeff_bf, const unsigned short* __restrict__ mem_bf,
    const unsigned short* __restrict__ memT,
    float* __restrict__ o_part, float* __restrict__ m_part, float* __restrict__ l_part) {
  const int h = blockIdx.x >> 6;
  const int b = (blockIdx.x >> 1) & 31;
  const int half = blockIdx.x & 1;
  const int tid = threadIdx.x;
  const int lane = tid & 63, w = tid >> 6;      // w in 0..3
  const int g = lane >> 4, q16 = lane & 15;

  __shared__ unsigned short mem_lds[64 * 256];    // [t][c], XOR-swizzled 16B chunks
  __shared__ unsigned short memT_lds[256 * 64];   // [c][t], XOR-swizzled 16B chunks
  __shared__ unsigned short p_lds[48 * PS3];
  __shared__ float red_m[4 * 48];                 // [w][q] transposed: conflict-free
  __shared__ float red_l[4 * 48];
  __shared__ float r_lds[48];

  // --- Q B-fragments direct bf16 (loop-invariant) ---
  bf16x8 bq[3][8];
#pragma unroll
  for (int qt = 0; qt < 3; ++qt) {
    const int ql = qt * 16 + q16;
    if (ql < 34) {
      const unsigned short* qbase = qkeff_bf + (size_t)(b * 34 + ql) * 2048 + h * 256;
#pragma unroll
      for (int ks = 0; ks < 8; ++ks)
        bq[qt][ks] = *reinterpret_cast<const bf16x8*>(qbase + ks * 32 + g * 8);
    } else {
#pragma unroll
      for (int ks = 0; ks < 8; ++ks) bq[qt][ks] = (bf16x8){0, 0, 0, 0, 0, 0, 0, 0};
    }
  }

  f32x4 ctx[3][4];
#pragma unroll
  for (int mt = 0; mt < 3; ++mt)
#pragma unroll
    for (int nt = 0; nt < 4; ++nt) ctx[mt][nt] = (f32x4){0.f, 0.f, 0.f, 0.f};
  float m_run[3] = {-1e30f, -1e30f, -1e30f};
  float l_run[3] = {0.f, 0.f, 0.f};

  const unsigned short* membb = mem_bf + (size_t)b * TSEQ * DD;
  const unsigned short* memTb = memT + (size_t)b * DD * TSEQ;

  for (int tile = 0; tile < 32; ++tile) {
    const int tbase = half * 2048 + tile * 64;
    __syncthreads();   // (A) previous tile fully consumed

    // --- stage mem tile 64x256 (32KB): 8 calls/wave, 1KB = 2 rows each ---
#pragma unroll
    for (int j = 0; j < 8; ++j) {
      const int cc = w * 8 + j;
      const int trow = cc * 2 + (lane >> 5);
      const int sc = (lane & 31) ^ (trow & 7);
      gload_lds16(membb + (size_t)(tbase + trow) * DD + sc * 8, &mem_lds[cc * 512]);
    }
    // --- stage memT tile 256x64 (32KB): 8 calls/wave, 1KB = 8 rows each ---
#pragma unroll
    for (int j = 0; j < 8; ++j) {
      const int cc = w * 8 + j;
      const int crow = cc * 8 + (lane >> 3);
      const int sc = (lane & 7) ^ (crow & 7);
      gload_lds16(memTb + (size_t)crow * TSEQ + tbase + sc * 8, &memT_lds[cc * 512]);
    }
    asm volatile("s_waitcnt vmcnt(0)" ::: "memory");
    __syncthreads();   // (B) staged

    // --- QK^T (swapped): wave w owns t-strip [w*16, w*16+16) ---
    f32x4 sacc[3];
#pragma unroll
    for (int qt = 0; qt < 3; ++qt) sacc[qt] = (f32x4){0.f, 0.f, 0.f, 0.f};
    {
      const int arow = w * 16 + q16;
      __builtin_amdgcn_s_setprio(1);
#pragma unroll
      for (int ks = 0; ks < 8; ++ks) {
        const bf16x8 af = *reinterpret_cast<const bf16x8*>(
            &mem_lds[arow * 256 + ((((ks << 2) + g) ^ (arow & 7)) << 3)]);
#pragma unroll
        for (int qt = 0; qt < 3; ++qt)
          sacc[qt] = __builtin_amdgcn_mfma_f32_16x16x32_bf16(af, bq[qt][ks], sacc[qt], 0, 0, 0);
      }
      __builtin_amdgcn_s_setprio(0);
    }

    // --- per-q max: in-lane 4, shfl over g, cross-wave via red_m[w][q] ---
#pragma unroll
    for (int qt = 0; qt < 3; ++qt) {
      float v = fmaxf(fmaxf(sacc[qt][0], sacc[qt][1]), fmaxf(sacc[qt][2], sacc[qt][3]));
      v = fmaxf(v, __shfl_xor(v, 16));
      v = fmaxf(v, __shfl_xor(v, 32));
      if (lane < 16) red_m[w * 48 + qt * 16 + lane] = v;
    }
    __syncthreads();   // (C) red_m ready

    float rfac[3], mnew[3];
#pragma unroll
    for (int qt = 0; qt < 3; ++qt) {
      const int q = qt * 16 + q16;
      const float tmax = fmaxf(fmaxf(red_m[q], red_m[48 + q]),
                               fmaxf(red_m[96 + q], red_m[144 + q]));
      mnew[qt] = fmaxf(m_run[qt], tmax);
      rfac[qt] = __expf(m_run[qt] - mnew[qt]);
      m_run[qt] = mnew[qt];
    }
    if (w == 0 && lane < 16) {
#pragma unroll
      for (int qt = 0; qt < 3; ++qt) r_lds[qt * 16 + lane] = rfac[qt];
    }

    // --- P = exp(S-m) -> p_lds bf16; partial sums -> red_l[w][q] ---
#pragma unroll
    for (int qt = 0; qt < 3; ++qt) {
      const float p0 = __expf(sacc[qt][0] - mnew[qt]);
      const float p1 = __expf(sacc[qt][1] - mnew[qt]);
      const float p2 = __expf(sacc[qt][2] - mnew[qt]);
      const float p3 = __expf(sacc[qt][3] - mnew[qt]);
      const int prow = (qt * 16 + q16) * PS3 + w * 16 + g * 4;
      *reinterpret_cast<unsigned*>(&p_lds[prow]) = cvtpk(p0, p1);
      *reinterpret_cast<unsigned*>(&p_lds[prow + 2]) = cvtpk(p2, p3);
      float ps = (p0 + p1) + (p2 + p3);
      ps += __shfl_xor(ps, 16);
      ps += __shfl_xor(ps, 32);
      if (lane < 16) red_l[w * 48 + qt * 16 + lane] = ps;
    }
    __syncthreads();   // (D) p_lds, red_l, r_lds ready

#pragma unroll
    for (int qt = 0; qt < 3; ++qt) {
      const int q = qt * 16 + q16;
      l_run[qt] = l_run[qt] * rfac[qt] +
                  ((red_l[q] + red_l[48 + q]) + (red_l[96 + q] + red_l[144 + q]));
    }
    // rescale ctx rows (row-mapped broadcast reads)
#pragma unroll
    for (int mt = 0; mt < 3; ++mt)
#pragma unroll
      for (int r = 0; r < 4; ++r) {
        const float rr = r_lds[mt * 16 + g * 4 + r];
#pragma unroll
        for (int nt = 0; nt < 4; ++nt) ctx[mt][nt][r] *= rr;
      }

    // --- PV: wave w owns c-slice [w*64, w*64+64) ---
    bf16x8 pf[3][2];
#pragma unroll
    for (int mt = 0; mt < 3; ++mt)
#pragma unroll
      for (int ks2 = 0; ks2 < 2; ++ks2)
        pf[mt][ks2] = *reinterpret_cast<const bf16x8*>(
            &p_lds[(mt * 16 + q16) * PS3 + ks2 * 32 + g * 8]);
    __builtin_amdgcn_s_setprio(1);
#pragma unroll
    for (int nt = 0; nt < 4; ++nt) {
      const int c = w * 64 + nt * 16 + q16;
#pragma unroll
      for (int ks2 = 0; ks2 < 2; ++ks2) {
        const bf16x8 bT = *reinterpret_cast<const bf16x8*>(
            &memT_lds[c * 64 + ((((ks2 << 2) + g) ^ (c & 7)) << 3)]);
#pragma unroll
        for (int mt = 0; mt < 3; ++mt)
          ctx[mt][nt] = __builtin_amdgcn_mfma_f32_16x16x32_bf16(pf[mt][ks2], bT,
                                                                ctx[mt][nt], 0, 0, 0);
      }
    }
    __builtin_amdgcn_s_setprio(0);
  }

  // --- write unnormalized o + (m,l) for this half ---
#pragma unroll
  for (int mt = 0; mt < 3; ++mt)
#pragma unroll
    for (int r = 0; r < 4; ++r) {
      const int q = mt * 16 + g * 4 + r;
      if (q < 34) {
        const size_t orow = (size_t)(half * ROWS + b * 34 + q) * 2048;
#pragma unroll
        for (int nt = 0; nt < 4; ++nt)
          o_part[orow + h * 256 + w * 64 + nt * 16 + q16] = ctx[mt][nt][r];
      }
    }
  if (w == 0 && lane < 16) {
#pragma unroll
    for (int qt = 0; qt < 3; ++qt) {
      const int q = qt * 16 + lane;
      if (q < 34) {
        const size_t idx = (size_t)(half * ROWS + b * 34 + q) * 8 + h;
        m_part[idx] = m_run[qt];
        l_part[idx] = l_run[qt];
      }
    }
  }
}

// ---------- combine the two T-halves -> ctx_bf ----------
__global__ __launch_bounds__(256) void ca_combine_kernel(
    const float* __restrict__ o_part, const float* __restrict__ m_part,
    const float* __restrict__ l_part, unsigned short* __restrict__ ctx_bf) {
  const int row = blockIdx.x, c = threadIdx.x;
#pragma unroll
  for (int h = 0; h < NHH; ++h) {
    const float m0 = m_part[(size_t)row * 8 + h];
    const float m1 = m_part[(size_t)(ROWS + row) * 8 + h];
    const float l0 = l_part[(size_t)row * 8 + h];
    const float l1 = l_part[(size_t)(ROWS + row) * 8 + h];
    const float M = fmaxf(m0, m1);
    const float w0 = __expf(m0 - M), w1 = __expf(m1 - M);
    const float denom = l0 * w0 + l1 * w1;
    const float o0 = o_part[(size_t)row * 2048 + h * 256 + c];
    const float o1 = o_part[(size_t)(ROWS + row) * 2048 + h * 256 + c];
    ctx_bf[(size_t)row * 2048 + h * 256 + c] = f2bf((o0 * w0 + o1 * w1) / denom);
  }
}

// ---------- refine pair-mean (fp32 in, bf16 out) ----------
__global__ __launch_bounds__(256) void pairmean_kernel(
    const float* __restrict__ u, const float* __restrict__ v,
    unsigned short* __restrict__ hbar_bf) {
  const int bp = blockIdx.x, tid = threadIdx.x;
  const int r0 = bp * KK;
  __shared__ float us[KK][132], vs[KK][132];
  for (int i = tid; i < KK * HIDD; i += 256) {
    const int r = i >> 7, f = i & 127;
    us[r][f] = u[(size_t)(r0 + r) * HIDD + f];
    vs[r][f] = v[(size_t)(r0 + r) * HIDD + f];
  }
  __syncthreads();
  for (int i = tid; i < KK * HIDD; i += 256) {
    const int r = i >> 7, f = i & 127;
    float s = 0.f;
#pragma unroll
    for (int j = 0; j < KK; ++j) s += fmaxf(us[r][f] + vs[j][f], 0.f);
    hbar_bf[(size_t)(r0 + r) * HIDD + f] = f2bf(s * (1.0f / 17.0f));
  }
}

static void gemm_bf(const unsigned short* X, const unsigned short* W, const float* bias,
                    const float* R, float* Yf, unsigned short* Ybf, int M, int N, int K,
                    int wstride, int relu, hipStream_t s) {
  dim3 g(N / 64, M / 64);
  gemm_bf16_kernel<<<g, 256, 0, s>>>(X, W, bias, R, Yf, Ybf, M, N, K, wstride, relu);
}
static void gemm_sk(const unsigned short* X, const unsigned short* W, float* part,
                    int M, int N, int K, int wstride, int ksplit, hipStream_t s) {
  dim3 g(N / 64, M / 64, ksplit);
  gemm_bf16_sk_kernel<<<g, 256, 0, s>>>(X, W, part, M, N, K, wstride, K / ksplit);
}

extern "C" void kernel_launch(void* const* d_in, const int* in_sizes, int n_in,
                              void* d_out, int out_size, void* d_ws, size_t ws_size,
                              hipStream_t stream) {
  const float* memory   = (const float*)d_in[0];
  const float* person_q = (const float*)d_in[1];
  const float* key_q    = (const float*)d_in[2];
  const float* sa_in_w  = (const float*)d_in[3];
  const float* sa_in_b  = (const float*)d_in[4];
  const float* sa_out_w = (const float*)d_in[5];
  const float* sa_out_b = (const float*)d_in[6];
  const float* ca_in_w  = (const float*)d_in[7];
  const float* ca_in_b  = (const float*)d_in[8];
  const float* ca_out_w = (const float*)d_in[9];
  const float* ca_out_b = (const float*)d_in[10];
  const float* ff1_w = (const float*)d_in[11];
  const float* ff1_b = (const float*)d_in[12];
  const float* ff2_w = (const float*)d_in[13];
  const float* ff2_b = (const float*)d_in[14];
  const float* ln1_w = (const float*)d_in[15];
  const float* ln1_b = (const float*)d_in[16];
  const float* ln2_w = (const float*)d_in[17];
  const float* ln2_b = (const float*)d_in[18];
  const float* ln3_w = (const float*)d_in[19];
  const float* ln3_b = (const float*)d_in[20];
  const float* r1_w1 = (const float*)d_in[21];
  const float* r1_b1 = (const float*)d_in[22];
  const float* r1_w2 = (const float*)d_in[23];
  const float* r1_b2 = (const float*)d_in[24];
  const float* r2_w1 = (const float*)d_in[25];
  const float* r2_b1 = (const float*)d_in[26];
  const float* r2_w2 = (const float*)d_in[27];
  const float* r2_b2 = (const float*)d_in[28];
  const float* fc_w  = (const float*)d_in[29];
  const float* fc_b  = (const float*)d_in[30];
  float* out = (float*)d_out;

  char* wsb = (char*)d_ws;
  size_t off = 0;
  auto alloc = [&](size_t bytes) -> char* {
    char* p = wsb + off;
    off += (bytes + 255) & ~(size_t)255;
    return p;
  };
  float* x      = (float*)alloc((size_t)ROWS * DD * 4);
  float* qkv    = (float*)alloc((size_t)ROWS * 768 * 4);
  float* parts  = (float*)alloc((size_t)4 * ROWS * DD * 4);
  float* bvo    = (float*)alloc(3 * 256 * 4);
  float* bqk    = (float*)alloc((size_t)3 * 2048 * 4);
  float* ubuf   = (float*)alloc((size_t)ROWS * HIDD * 4);
  float* vbuf   = (float*)alloc((size_t)ROWS * HIDD * 4);
  float* o_part = (float*)alloc((size_t)2 * ROWS * 2048 * 4);
  float* m_part = (float*)alloc((size_t)2 * ROWS * 8 * 4);
  float* l_part = (float*)alloc((size_t)2 * ROWS * 8 * 4);
  unsigned short* x_bf     = (unsigned short*)alloc((size_t)ROWS * DD * 2);
  unsigned short* attn_bf  = (unsigned short*)alloc((size_t)ROWS * DD * 2);
  unsigned short* hff_bf   = (unsigned short*)alloc((size_t)ROWS * 2048 * 2);
  unsigned short* ctx_bf   = (unsigned short*)alloc((size_t)ROWS * 2048 * 2);
  unsigned short* qkeff_bf = (unsigned short*)alloc((size_t)ROWS * 2048 * 2);
  unsigned short* hbar_bf  = (unsigned short*)alloc((size_t)ROWS * HIDD * 2);
  unsigned short* mem_bf   = (unsigned short*)alloc((size_t)NB * TSEQ * DD * 2);
  unsigned short* memT     = (unsigned short*)alloc((size_t)NB * TSEQ * DD * 2);
  unsigned short* sa_in_bf  = (unsigned short*)alloc((size_t)3 * 768 * 256 * 2);
  unsigned short* sa_out_bf = (unsigned short*)alloc((size_t)3 * 256 * 256 * 2);
  unsigned short* Wqk_bf   = (unsigned short*)alloc((size_t)3 * 2048 * 256 * 2);
  unsigned short* ff1_bf   = (unsigned short*)alloc((size_t)3 * 2048 * 256 * 2);
  unsigned short* ff2_bf   = (unsigned short*)alloc((size_t)3 * 256 * 2048 * 2);
  unsigned short* Wvo_bf   = (unsigned short*)alloc((size_t)3 * 256 * 2048 * 2);
  unsigned short* r1w1_bf  = (unsigned short*)alloc((size_t)HIDD * 512 * 2);
  unsigned short* r1w2_bf  = (unsigned short*)alloc((size_t)DD * HIDD * 2);
  unsigned short* r2w1_bf  = (unsigned short*)alloc((size_t)HIDD * 512 * 2);
  unsigned short* r2w2_bf  = (unsigned short*)alloc((size_t)DD * HIDD * 2);

  // ---- prep ----
  prep_mem_kernel<<<NB * 64, 256, 0, stream>>>(memory, mem_bf, memT);
  CvtJobs8 jobs;
  jobs.j[0] = {sa_in_w,  sa_in_bf,  3 * 768 * 256};
  jobs.j[1] = {sa_out_w, sa_out_bf, 3 * 256 * 256};
  jobs.j[2] = {ff1_w,    ff1_bf,    3 * 2048 * 256};
  jobs.j[3] = {ff2_w,    ff2_bf,    3 * 256 * 2048};
  jobs.j[4] = {r1_w1,    r1w1_bf,   HIDD * 512};
  jobs.j[5] = {r1_w2,    r1w2_bf,   DD * HIDD};
  jobs.j[6] = {r2_w1,    r2w1_bf,   HIDD * 512};
  jobs.j[7] = {r2_w2,    r2w2_bf,   DD * HIDD};
  cvt_multi_kernel<<<1024, 256, 0, stream>>>(jobs);
  wqkvo_kernel<<<12288, 256, 0, stream>>>(ca_in_w, ca_out_w, Wqk_bf, Wvo_bf);
  prep_small_kernel<<<ROWS + 24 + 3, 256, 0, stream>>>(
      person_q, key_q, ca_in_w, ca_in_b, ca_out_w, ca_out_b, x, x_bf, bqk, bvo);

  for (int l = 0; l < LL; ++l) {
    // --- self-attention ---
    gemm_bf(x_bf, sa_in_bf + (size_t)l * 768 * 256, sa_in_b + l * 768, nullptr,
            qkv, nullptr, ROWS, 768, 256, 256, 0, stream);
    sa_attn_kernel<<<512, 64, 0, stream>>>(qkv, attn_bf);
    gemm_sk(attn_bf, sa_out_bf + (size_t)l * 256 * 256, parts,
            ROWS, 256, 256, 256, 2, stream);
    ln_red_kernel<<<ROWS, 256, 0, stream>>>(x, parts, 2, sa_out_b + l * 256,
                                            ln1_w + l * 256, ln1_b + l * 256, x, x_bf);
    // --- cross-attention: qk_eff = x @ Wqk^T + bqk (scale folded) ---
    gemm_bf(x_bf, Wqk_bf + (size_t)l * 2048 * 256, bqk + l * 2048, nullptr,
            nullptr, qkeff_bf, ROWS, 2048, 256, 256, 0, stream);
    ca_fused_kernel<<<512, 256, 0, stream>>>(qkeff_bf, mem_bf, memT, o_part, m_part, l_part);
    ca_combine_kernel<<<ROWS, 256, 0, stream>>>(o_part, m_part, l_part, ctx_bf);
    gemm_sk(ctx_bf, Wvo_bf + (size_t)l * 256 * 2048, parts,
            ROWS, 256, 2048, 2048, 4, stream);
    ln_red_kernel<<<ROWS, 256, 0, stream>>>(x, parts, 4, bvo + l * 256,
                                            ln2_w + l * 256, ln2_b + l * 256, x, x_bf);
    // --- feed-forward ---
    gemm_bf(x_bf, ff1_bf + (size_t)l * 2048 * 256, ff1_b + l * 2048, nullptr,
            nullptr, hff_bf, ROWS, 2048, 256, 256, 1, stream);
    gemm_sk(hff_bf, ff2_bf + (size_t)l * 256 * 2048, parts,
            ROWS, 256, 2048, 2048, 4, stream);
    ln_red_kernel<<<ROWS, 256, 0, stream>>>(x, parts, 4, ff2_b + l * 256,
                                            ln3_w + l * 256, ln3_b + l * 256, x, x_bf);
  }

  // --- two refine blocks (bf16 MFMA) ---
  const unsigned short* rw1_bf[2] = {r1w1_bf, r2w1_bf};
  const unsigned short* rw2_bf[2] = {r1w2_bf, r2w2_bf};
  const float* rb1[2] = {r1_b1, r2_b1};
  const float* rb2[2] = {r1_b2, r2_b2};
  for (int r = 0; r < 2; ++r) {
    gemm_bf(x_bf, rw1_bf[r], rb1[r], nullptr, ubuf, nullptr,
            ROWS, 128, 256, 512, 0, stream);
    gemm_bf(x_bf, rw1_bf[r] + 256, nullptr, nullptr, vbuf, nullptr,
            ROWS, 128, 256, 512, 0, stream);
    pairmean_kernel<<<64, 256, 0, stream>>>(ubuf, vbuf, hbar_bf);
    gemm_bf(hbar_bf, rw2_bf[r], rb2[r], x, x, x_bf,
            ROWS, 256, 128, 128, 0, stream);
  }

  // --- final fc ---
  fc_kernel<<<ROWS / 4, 256, 0, stream>>>(x, fc_w, fc_b, out);
}

// Round 13
// 637.448 us; speedup vs baseline: 1.4076x; 1.0398x over previous
//
#include <hip/hip_runtime.h>
#include <stdint.h>

// Problem constants
#define NB   32
#define TSEQ 4096
#define DD   256
#define PP   2
#define KK   17
#define LL   3
#define NHH  8
#define HDD  32
#define FFD  2048
#define HIDD 128
#define ROWS 1088                    // B*P*K
#define SCALE 0.17677669529663689f   // 1/sqrt(32)

typedef __attribute__((ext_vector_type(4))) float f32x4;
typedef __attribute__((ext_vector_type(8))) short bf16x8;

static __device__ __forceinline__ unsigned cvtpk(float lo, float hi) {
  unsigned r;
  asm volatile("v_cvt_pk_bf16_f32 %0, %1, %2" : "=v"(r) : "v"(lo), "v"(hi));
  return r;
}
static __device__ __forceinline__ unsigned short f2bf(float f) {
  unsigned int x = __float_as_uint(f);
  return (unsigned short)((x + 0x7fffu + ((x >> 16) & 1u)) >> 16);
}
static __device__ __forceinline__ void gload_lds16(const void* g, void* l) {
  __builtin_amdgcn_global_load_lds(
      (const __attribute__((address_space(1))) unsigned int*)g,
      (__attribute__((address_space(3))) unsigned int*)l, 16, 0, 0);
}

// ---------- batched fp32 -> bf16 convert (8 jobs in one launch) ----------
struct CvtJob { const float* src; unsigned short* dst; int n; };
struct CvtJobs8 { CvtJob j[8]; };
__global__ __launch_bounds__(256) void cvt_multi_kernel(CvtJobs8 jobs) {
#pragma unroll
  for (int jj = 0; jj < 8; ++jj) {
    const float* src = jobs.j[jj].src;
    unsigned short* dst = jobs.j[jj].dst;
    const int n8 = jobs.j[jj].n >> 3;
    for (int i = blockIdx.x * 256 + threadIdx.x; i < n8; i += gridDim.x * 256) {
      const float4 f0 = *reinterpret_cast<const float4*>(src + i * 8);
      const float4 f1 = *reinterpret_cast<const float4*>(src + i * 8 + 4);
      uint4 st;
      st.x = cvtpk(f0.x, f0.y); st.y = cvtpk(f0.z, f0.w);
      st.z = cvtpk(f1.x, f1.y); st.w = cvtpk(f1.z, f1.w);
      *reinterpret_cast<uint4*>(dst + i * 8) = st;
    }
  }
}

// ---------- merged small prep: init_x (1088) + bqk (24) + bvo (3) ----------
__global__ __launch_bounds__(256) void prep_small_kernel(
    const float* __restrict__ person_q, const float* __restrict__ key_q,
    const float* __restrict__ ca_in_w, const float* __restrict__ ca_in_b,
    const float* __restrict__ ca_out_w, const float* __restrict__ ca_out_b,
    float* __restrict__ x, unsigned short* __restrict__ x_bf,
    float* __restrict__ bqk, float* __restrict__ bvo) {
  const int bx = blockIdx.x, tid = threadIdx.x;
  if (bx < ROWS) {
    const int p = (bx / KK) & 1, k = bx % KK;
    const float v = person_q[p * DD + tid] + key_q[k * DD + tid];
    x[(size_t)bx * DD + tid] = v;
    x_bf[(size_t)bx * DD + tid] = f2bf(v);
  } else if (bx < ROWS + 24) {
    const int b2 = bx - ROWS;
    const int l = b2 >> 3, h = b2 & 7;
    const float* Wk = ca_in_w + (size_t)l * 196608 + (size_t)(256 + h * 32) * 256;
    const float* bq = ca_in_b + l * 768 + h * 32;
    float acc = 0.f;
#pragma unroll
    for (int j = 0; j < 32; ++j) acc += bq[j] * Wk[(size_t)j * 256 + tid];
    bqk[(size_t)l * 2048 + h * 256 + tid] = acc * SCALE;
  } else {
    const int l = bx - ROWS - 24;
    float acc = ca_out_b[l * 256 + tid];
    for (int j = 0; j < 256; ++j)
      acc += ca_out_w[(size_t)l * 65536 + (size_t)tid * 256 + j] * ca_in_b[l * 768 + 512 + j];
    bvo[l * 256 + tid] = acc;
  }
}

// ---------- bf16 MFMA GEMM: Y = act(Xbf @ Wbf^T + bias) [+ R] ----------
// M,N,K multiples of 64. 64x64 tile, 4 waves. (single-buffered: best measured)
__global__ __launch_bounds__(256) void gemm_bf16_kernel(
    const unsigned short* __restrict__ Xbf, const unsigned short* __restrict__ Wbf,
    const float* __restrict__ bias, const float* __restrict__ R,
    float* __restrict__ Yf, unsigned short* __restrict__ Ybf,
    int M, int N, int K, int wstride, int relu) {
  __shared__ unsigned short Xs[64 * 64];
  __shared__ unsigned short Ws[64 * 64];
  const int tid = threadIdx.x, lane = tid & 63, w = tid >> 6;
  const int g = lane >> 4, q16 = lane & 15;
  const int m0 = blockIdx.y * 64, n0 = blockIdx.x * 64;
  f32x4 acc[4];
#pragma unroll
  for (int nt = 0; nt < 4; ++nt) acc[nt] = (f32x4){0.f, 0.f, 0.f, 0.f};

  for (int k0 = 0; k0 < K; k0 += 64) {
    __syncthreads();
#pragma unroll
    for (int j = 0; j < 2; ++j) {
      const int cc = w * 2 + j;
      const int row = cc * 8 + (lane >> 3);
      const int sc = (lane & 7) ^ (row & 7);
      gload_lds16(Xbf + (size_t)(m0 + row) * K + k0 + sc * 8, &Xs[cc * 512]);
      gload_lds16(Wbf + (size_t)(n0 + row) * wstride + k0 + sc * 8, &Ws[cc * 512]);
    }
    asm volatile("s_waitcnt vmcnt(0)" ::: "memory");
    __syncthreads();
    const int arow = w * 16 + q16;
#pragma unroll
    for (int ks = 0; ks < 2; ++ks) {
      const bf16x8 a = *reinterpret_cast<const bf16x8*>(
          &Xs[arow * 64 + ((((ks << 2) + g) ^ (arow & 7)) << 3)]);
#pragma unroll
      for (int nt = 0; nt < 4; ++nt) {
        const int brow = nt * 16 + q16;
        const bf16x8 bfr = *reinterpret_cast<const bf16x8*>(
            &Ws[brow * 64 + ((((ks << 2) + g) ^ (brow & 7)) << 3)]);
        acc[nt] = __builtin_amdgcn_mfma_f32_16x16x32_bf16(a, bfr, acc[nt], 0, 0, 0);
      }
    }
  }
#pragma unroll
  for (int nt = 0; nt < 4; ++nt) {
    const int n = n0 + nt * 16 + q16;
    const float bv = bias ? bias[n] : 0.f;
#pragma unroll
    for (int r = 0; r < 4; ++r) {
      const int m = m0 + w * 16 + g * 4 + r;
      float o = acc[nt][r] + bv;
      if (relu) o = fmaxf(o, 0.f);
      if (R) o += R[(size_t)m * N + n];
      if (Yf) Yf[(size_t)m * N + n] = o;
      if (Ybf) Ybf[(size_t)m * N + n] = f2bf(o);
    }
  }
}

// ---------- split-K bf16 MFMA GEMM: part[kz] = Xbf[:,kz*ksl:(kz+1)*ksl] @ W^T ----------
__global__ __launch_bounds__(256) void gemm_bf16_sk_kernel(
    const unsigned short* __restrict__ Xbf, const unsigned short* __restrict__ Wbf,
    float* __restrict__ part, int M, int N, int K, int wstride, int kslice) {
  __shared__ unsigned short Xs[64 * 64];
  __shared__ unsigned short Ws[64 * 64];
  const int tid = threadIdx.x, lane = tid & 63, w = tid >> 6;
  const int g = lane >> 4, q16 = lane & 15;
  const int m0 = blockIdx.y * 64, n0 = blockIdx.x * 64;
  const int kz = blockIdx.z;
  const int kbeg = kz * kslice, kend = kbeg + kslice;
  f32x4 acc[4];
#pragma unroll
  for (int nt = 0; nt < 4; ++nt) acc[nt] = (f32x4){0.f, 0.f, 0.f, 0.f};

  for (int k0 = kbeg; k0 < kend; k0 += 64) {
    __syncthreads();
#pragma unroll
    for (int j = 0; j < 2; ++j) {
      const int cc = w * 2 + j;
      const int row = cc * 8 + (lane >> 3);
      const int sc = (lane & 7) ^ (row & 7);
      gload_lds16(Xbf + (size_t)(m0 + row) * K + k0 + sc * 8, &Xs[cc * 512]);
      gload_lds16(Wbf + (size_t)(n0 + row) * wstride + k0 + sc * 8, &Ws[cc * 512]);
    }
    asm volatile("s_waitcnt vmcnt(0)" ::: "memory");
    __syncthreads();
    const int arow = w * 16 + q16;
#pragma unroll
    for (int ks = 0; ks < 2; ++ks) {
      const bf16x8 a = *reinterpret_cast<const bf16x8*>(
          &Xs[arow * 64 + ((((ks << 2) + g) ^ (arow & 7)) << 3)]);
#pragma unroll
      for (int nt = 0; nt < 4; ++nt) {
        const int brow = nt * 16 + q16;
        const bf16x8 bfr = *reinterpret_cast<const bf16x8*>(
            &Ws[brow * 64 + ((((ks << 2) + g) ^ (brow & 7)) << 3)]);
        acc[nt] = __builtin_amdgcn_mfma_f32_16x16x32_bf16(a, bfr, acc[nt], 0, 0, 0);
      }
    }
  }
  float* pout = part + (size_t)kz * M * N;
#pragma unroll
  for (int nt = 0; nt < 4; ++nt) {
    const int n = n0 + nt * 16 + q16;
#pragma unroll
    for (int r = 0; r < 4; ++r) {
      const int m = m0 + w * 16 + g * 4 + r;
      pout[(size_t)m * N + n] = acc[nt][r];
    }
  }
}

// ---------- reduce split-K partials + bias + residual + LayerNorm ----------
__global__ __launch_bounds__(256) void ln_red_kernel(
    const float* __restrict__ xin, const float* __restrict__ parts, int np,
    const float* __restrict__ bias, const float* __restrict__ w,
    const float* __restrict__ b, float* __restrict__ xout,
    unsigned short* __restrict__ xout_bf) {
  const int row = blockIdx.x, tid = threadIdx.x;
  const size_t base = (size_t)row * DD + tid;
  float v = xin[base] + bias[tid];
  for (int p = 0; p < np; ++p) v += parts[(size_t)p * ROWS * DD + base];
  float s = v, s2 = v * v;
#pragma unroll
  for (int off = 32; off > 0; off >>= 1) {
    s += __shfl_down(s, off);
    s2 += __shfl_down(s2, off);
  }
  __shared__ float ps[4], ps2[4];
  if ((tid & 63) == 0) { ps[tid >> 6] = s; ps2[tid >> 6] = s2; }
  __syncthreads();
  const float st = ps[0] + ps[1] + ps[2] + ps[3];
  const float st2 = ps2[0] + ps2[1] + ps2[2] + ps2[3];
  const float mean = st * (1.f / 256.f);
  const float var = st2 * (1.f / 256.f) - mean * mean;
  const float inv = rsqrtf(var + 1e-5f);
  const float o = (v - mean) * inv * w[tid] + b[tid];
  xout[base] = o;
  xout_bf[base] = f2bf(o);
}

// ---------- final fc: out[m][0..2] = x[m] . fc_w[o] + fc_b[o] ----------
__global__ __launch_bounds__(256) void fc_kernel(
    const float* __restrict__ x, const float* __restrict__ fc_w,
    const float* __restrict__ fc_b, float* __restrict__ out) {
  const int row = blockIdx.x * 4 + (threadIdx.x >> 6);
  const int lane = threadIdx.x & 63;
  float xr[4];
#pragma unroll
  for (int j = 0; j < 4; ++j) xr[j] = x[(size_t)row * DD + lane + 64 * j];
#pragma unroll
  for (int o = 0; o < 3; ++o) {
    float s = 0.f;
#pragma unroll
    for (int j = 0; j < 4; ++j) s += xr[j] * fc_w[o * DD + lane + 64 * j];
#pragma unroll
    for (int off = 32; off > 0; off >>= 1) s += __shfl_down(s, off);
    if (lane == 0) out[(size_t)row * 3 + o] = s + fc_b[o];
  }
}

// ---------- self-attention over K=17 keypoints (bf16 out) ----------
__global__ __launch_bounds__(64) void sa_attn_kernel(
    const float* __restrict__ qkv, unsigned short* __restrict__ attn_bf) {
  const int blk = blockIdx.x;
  const int h = blk & 7, bp = blk >> 3;
  const int rowbase = bp * KK;
  const int tid = threadIdx.x;
  __shared__ float qs[KK][36], ks[KK][36], vs[KK][36];
  __shared__ float ss[KK][20];
  __shared__ float lsum[KK];
  for (int i = tid; i < KK * HDD; i += 64) {
    const int r = i >> 5, d = i & 31;
    const size_t base = (size_t)(rowbase + r) * 768 + h * 32 + d;
    qs[r][d] = qkv[base];
    ks[r][d] = qkv[base + 256];
    vs[r][d] = qkv[base + 512];
  }
  __syncthreads();
  for (int i = tid; i < KK * KK; i += 64) {
    const int q = i / KK, k = i % KK;
    float s = 0.f;
#pragma unroll
    for (int d = 0; d < HDD; ++d) s += qs[q][d] * ks[k][d];
    ss[q][k] = s * SCALE;
  }
  __syncthreads();
  if (tid < KK) {
    float m = -1e30f;
    for (int k = 0; k < KK; ++k) m = fmaxf(m, ss[tid][k]);
    float l = 0.f;
    for (int k = 0; k < KK; ++k) { const float e = __expf(ss[tid][k] - m); ss[tid][k] = e; l += e; }
    lsum[tid] = l;
  }
  __syncthreads();
  for (int i = tid; i < KK * HDD; i += 64) {
    const int q = i >> 5, d = i & 31;
    float o = 0.f;
#pragma unroll
    for (int k = 0; k < KK; ++k) o += ss[q][k] * vs[k][d];
    attn_bf[(size_t)(rowbase + q) * DD + h * 32 + d] = f2bf(o / lsum[q]);
  }
}

// ---------- merged Wqk + Wvo folding + refine-w1 packing (grid 12800) ----------
__global__ __launch_bounds__(256) void wqkvo_kernel(
    const float* __restrict__ ca_in_w, const float* __restrict__ ca_out_w,
    const float* __restrict__ r1_w1, const float* __restrict__ r2_w1,
    unsigned short* __restrict__ Wqk_bf, unsigned short* __restrict__ Wvo_bf,
    unsigned short* __restrict__ rpack_bf) {
  const int bx0 = blockIdx.x;
  if (bx0 < 6144) {
    const int l = bx0 >> 11, hc = bx0 & 2047;
    const int h = hc >> 8, c = hc & 255;
    const int d = threadIdx.x;
    const float* Wq = ca_in_w + (size_t)l * 196608 + (size_t)(h * 32) * 256;
    const float* Wk = ca_in_w + (size_t)l * 196608 + (size_t)(256 + h * 32) * 256;
    float acc = 0.f;
#pragma unroll
    for (int j = 0; j < 32; ++j) acc += Wk[(size_t)j * 256 + c] * Wq[(size_t)j * 256 + d];
    Wqk_bf[((size_t)l * 2048 + hc) * 256 + d] = f2bf(acc * SCALE);
  } else if (bx0 < 12288) {
    const int bx = bx0 - 6144;
    const int h = bx & 7, dp = (bx >> 3) & 255, l = bx >> 11;
    const int c = threadIdx.x;
    const float* wout = ca_out_w + (size_t)l * 65536 + (size_t)dp * 256 + h * 32;
    const float* wv = ca_in_w + (size_t)l * 196608 + (size_t)(512 + h * 32) * 256 + c;
    float acc = 0.f;
#pragma unroll
    for (int j = 0; j < 32; ++j) acc += wout[j] * wv[(size_t)j * 256];
    Wvo_bf[((size_t)l * 256 + dp) * 2048 + h * 256 + c] = f2bf(acc);
  } else {
    // pack refine w1: rows 0..127 = W1a (cols 0..255), rows 128..255 = W1b (cols 256..511)
    const int bx2 = bx0 - 12288;            // 0..511
    const int rr = bx2 >> 8, n = bx2 & 255;
    const float* w1 = rr ? r2_w1 : r1_w1;
    const float v = (n < 128) ? w1[(size_t)n * 512 + threadIdx.x]
                              : w1[(size_t)(n - 128) * 512 + 256 + threadIdx.x];
    rpack_bf[(size_t)rr * 65536 + (size_t)n * 256 + threadIdx.x] = f2bf(v);
  }
}

// ---------- prep: mem_bf[b][t][c] + memT[b][c][t] (both bf16) ----------
__global__ __launch_bounds__(256) void prep_mem_kernel(
    const float* __restrict__ memory, unsigned short* __restrict__ mem_bf,
    unsigned short* __restrict__ memT) {
  const int b = blockIdx.x >> 6, tc = blockIdx.x & 63;
  const int tid = threadIdx.x;
  __shared__ unsigned short tile[64][264];
  for (int it = 0; it < 8; ++it) {
    const int idx = it * 256 + tid;
    const int t = idx >> 5, c8 = (idx & 31) << 3;
    const size_t goff = ((size_t)b * TSEQ + tc * 64 + t) * DD + c8;
    const float4 f0 = *reinterpret_cast<const float4*>(memory + goff);
    const float4 f1 = *reinterpret_cast<const float4*>(memory + goff + 4);
    uint4 st;
    st.x = cvtpk(f0.x, f0.y); st.y = cvtpk(f0.z, f0.w);
    st.z = cvtpk(f1.x, f1.y); st.w = cvtpk(f1.z, f1.w);
    *reinterpret_cast<uint4*>(&tile[t][c8]) = st;
    *reinterpret_cast<uint4*>(mem_bf + goff) = st;
  }
  __syncthreads();
  for (int it = 0; it < 8; ++it) {
    const int idx = it * 256 + tid;
    const int c = idx >> 3, t8 = (idx & 7) << 3;
    union { unsigned short v[8]; uint4 u; } pk;
#pragma unroll
    for (int j = 0; j < 8; ++j) pk.v[j] = tile[t8 + j][c];
    *reinterpret_cast<uint4*>(&memT[((size_t)b * DD + c) * TSEQ + tc * 64 + t8]) = pk.u;
  }
}

// ---------- fused MFMA cross-attention flash (v4 + defer-max) ----------
// grid 512: bid = h*64 + b*2 + half -> 8 heads of same (b,half) share bid%8 (XCD).
// 256 threads = 4 waves, t-tile 64, 32 tiles per block. LDS 74KB -> 2 blocks/CU.
// Defer-max (T13, THR=8): when __all(tmax - m_run <= 8) skip rescale/r_lds/max
// update. Decision is identical across waves (all read the same red_m with
// identical m_run history), so branching is block-uniform.
#define PS3 72
__global__ __launch_bounds__(256, 2) void ca_fused_kernel(
    const unsigned short* __restrict__ qkeff_bf, const unsigned short* __restrict__ mem_bf,
    const unsigned short* __restrict__ memT,
    float* __restrict__ o_part, float* __restrict__ m_part, float* __restrict__ l_part) {
  const int h = blockIdx.x >> 6;
  const int b = (blockIdx.x >> 1) & 31;
  const int half = blockIdx.x & 1;
  const int tid = threadIdx.x;
  const int lane = tid & 63, w = tid >> 6;      // w in 0..3
  const int g = lane >> 4, q16 = lane & 15;

  __shared__ unsigned short mem_lds[64 * 256];    // [t][c], XOR-swizzled 16B chunks
  __shared__ unsigned short memT_lds[256 * 64];   // [c][t], XOR-swizzled 16B chunks
  __shared__ unsigned short p_lds[48 * PS3];
  __shared__ float red_m[4 * 48];                 // [w][q] transposed: conflict-free
  __shared__ float red_l[4 * 48];
  __shared__ float r_lds[48];

  // --- Q B-fragments direct bf16 (loop-invariant) ---
  bf16x8 bq[3][8];
#pragma unroll
  for (int qt = 0; qt < 3; ++qt) {
    const int ql = qt * 16 + q16;
    if (ql < 34) {
      const unsigned short* qbase = qkeff_bf + (size_t)(b * 34 + ql) * 2048 + h * 256;
#pragma unroll
      for (int ks = 0; ks < 8; ++ks)
        bq[qt][ks] = *reinterpret_cast<const bf16x8*>(qbase + ks * 32 + g * 8);
    } else {
#pragma unroll
      for (int ks = 0; ks < 8; ++ks) bq[qt][ks] = (bf16x8){0, 0, 0, 0, 0, 0, 0, 0};
    }
  }

  f32x4 ctx[3][4];
#pragma unroll
  for (int mt = 0; mt < 3; ++mt)
#pragma unroll
    for (int nt = 0; nt < 4; ++nt) ctx[mt][nt] = (f32x4){0.f, 0.f, 0.f, 0.f};
  float m_run[3] = {-1e30f, -1e30f, -1e30f};
  float l_run[3] = {0.f, 0.f, 0.f};

  const unsigned short* membb = mem_bf + (size_t)b * TSEQ * DD;
  const unsigned short* memTb = memT + (size_t)b * DD * TSEQ;

  for (int tile = 0; tile < 32; ++tile) {
    const int tbase = half * 2048 + tile * 64;
    __syncthreads();   // (A) previous tile fully consumed

    // --- stage mem tile 64x256 (32KB): 8 calls/wave, 1KB = 2 rows each ---
#pragma unroll
    for (int j = 0; j < 8; ++j) {
      const int cc = w * 8 + j;
      const int trow = cc * 2 + (lane >> 5);
      const int sc = (lane & 31) ^ (trow & 7);
      gload_lds16(membb + (size_t)(tbase + trow) * DD + sc * 8, &mem_lds[cc * 512]);
    }
    // --- stage memT tile 256x64 (32KB): 8 calls/wave, 1KB = 8 rows each ---
#pragma unroll
    for (int j = 0; j < 8; ++j) {
      const int cc = w * 8 + j;
      const int crow = cc * 8 + (lane >> 3);
      const int sc = (lane & 7) ^ (crow & 7);
      gload_lds16(memTb + (size_t)crow * TSEQ + tbase + sc * 8, &memT_lds[cc * 512]);
    }
    asm volatile("s_waitcnt vmcnt(0)" ::: "memory");
    __syncthreads();   // (B) staged

    // --- QK^T (swapped): wave w owns t-strip [w*16, w*16+16) ---
    f32x4 sacc[3];
#pragma unroll
    for (int qt = 0; qt < 3; ++qt) sacc[qt] = (f32x4){0.f, 0.f, 0.f, 0.f};
    {
      const int arow = w * 16 + q16;
      __builtin_amdgcn_s_setprio(1);
#pragma unroll
      for (int ks = 0; ks < 8; ++ks) {
        const bf16x8 af = *reinterpret_cast<const bf16x8*>(
            &mem_lds[arow * 256 + ((((ks << 2) + g) ^ (arow & 7)) << 3)]);
#pragma unroll
        for (int qt = 0; qt < 3; ++qt)
          sacc[qt] = __builtin_amdgcn_mfma_f32_16x16x32_bf16(af, bq[qt][ks], sacc[qt], 0, 0, 0);
      }
      __builtin_amdgcn_s_setprio(0);
    }

    // --- per-q max: in-lane 4, shfl over g, cross-wave via red_m[w][q] ---
#pragma unroll
    for (int qt = 0; qt < 3; ++qt) {
      float v = fmaxf(fmaxf(sacc[qt][0], sacc[qt][1]), fmaxf(sacc[qt][2], sacc[qt][3]));
      v = fmaxf(v, __shfl_xor(v, 16));
      v = fmaxf(v, __shfl_xor(v, 32));
      if (lane < 16) red_m[w * 48 + qt * 16 + lane] = v;
    }
    __syncthreads();   // (C) red_m ready

    float tmax[3];
#pragma unroll
    for (int qt = 0; qt < 3; ++qt) {
      const int q = qt * 16 + q16;
      tmax[qt] = fmaxf(fmaxf(red_m[q], red_m[48 + q]),
                       fmaxf(red_m[96 + q], red_m[144 + q]));
    }
    const float dmax = fmaxf(fmaxf(tmax[0] - m_run[0], tmax[1] - m_run[1]),
                             tmax[2] - m_run[2]);
    const bool defer = __all(dmax <= 8.0f);   // block-uniform (see header comment)
    float rfac[3] = {1.f, 1.f, 1.f};
    if (!defer) {
#pragma unroll
      for (int qt = 0; qt < 3; ++qt) {
        const float mnew = fmaxf(m_run[qt], tmax[qt]);
        rfac[qt] = __expf(m_run[qt] - mnew);
        m_run[qt] = mnew;
      }
      if (w == 0 && lane < 16) {
#pragma unroll
        for (int qt = 0; qt < 3; ++qt) r_lds[qt * 16 + lane] = rfac[qt];
      }
    }

    // --- P = exp(S-m) -> p_lds bf16; partial sums -> red_l[w][q] ---
#pragma unroll
    for (int qt = 0; qt < 3; ++qt) {
      const float p0 = __expf(sacc[qt][0] - m_run[qt]);
      const float p1 = __expf(sacc[qt][1] - m_run[qt]);
      const float p2 = __expf(sacc[qt][2] - m_run[qt]);
      const float p3 = __expf(sacc[qt][3] - m_run[qt]);
      const int prow = (qt * 16 + q16) * PS3 + w * 16 + g * 4;
      *reinterpret_cast<unsigned*>(&p_lds[prow]) = cvtpk(p0, p1);
      *reinterpret_cast<unsigned*>(&p_lds[prow + 2]) = cvtpk(p2, p3);
      float ps = (p0 + p1) + (p2 + p3);
      ps += __shfl_xor(ps, 16);
      ps += __shfl_xor(ps, 32);
      if (lane < 16) red_l[w * 48 + qt * 16 + lane] = ps;
    }
    __syncthreads();   // (D) p_lds, red_l, r_lds ready

#pragma unroll
    for (int qt = 0; qt < 3; ++qt) {
      const int q = qt * 16 + q16;
      const float ssum = (red_l[q] + red_l[48 + q]) + (red_l[96 + q] + red_l[144 + q]);
      l_run[qt] = defer ? (l_run[qt] + ssum) : (l_run[qt] * rfac[qt] + ssum);
    }
    if (!defer) {
      // rescale ctx rows (row-mapped broadcast reads)
#pragma unroll
      for (int mt = 0; mt < 3; ++mt)
#pragma unroll
        for (int r = 0; r < 4; ++r) {
          const float rr = r_lds[mt * 16 + g * 4 + r];
#pragma unroll
          for (int nt = 0; nt < 4; ++nt) ctx[mt][nt][r] *= rr;
        }
    }

    // --- PV: wave w owns c-slice [w*64, w*64+64) ---
    bf16x8 pf[3][2];
#pragma unroll
    for (int mt = 0; mt < 3; ++mt)
#pragma unroll
      for (int ks2 = 0; ks2 < 2; ++ks2)
        pf[mt][ks2] = *reinterpret_cast<const bf16x8*>(
            &p_lds[(mt * 16 + q16) * PS3 + ks2 * 32 + g * 8]);
    __builtin_amdgcn_s_setprio(1);
#pragma unroll
    for (int nt = 0; nt < 4; ++nt) {
      const int c = w * 64 + nt * 16 + q16;
#pragma unroll
      for (int ks2 = 0; ks2 < 2; ++ks2) {
        const bf16x8 bT = *reinterpret_cast<const bf16x8*>(
            &memT_lds[c * 64 + ((((ks2 << 2) + g) ^ (c & 7)) << 3)]);
#pragma unroll
        for (int mt = 0; mt < 3; ++mt)
          ctx[mt][nt] = __builtin_amdgcn_mfma_f32_16x16x32_bf16(pf[mt][ks2], bT,
                                                                ctx[mt][nt], 0, 0, 0);
      }
    }
    __builtin_amdgcn_s_setprio(0);
  }

  // --- write unnormalized o + (m,l) for this half ---
#pragma unroll
  for (int mt = 0; mt < 3; ++mt)
#pragma unroll
    for (int r = 0; r < 4; ++r) {
      const int q = mt * 16 + g * 4 + r;
      if (q < 34) {
        const size_t orow = (size_t)(half * ROWS + b * 34 + q) * 2048;
#pragma unroll
        for (int nt = 0; nt < 4; ++nt)
          o_part[orow + h * 256 + w * 64 + nt * 16 + q16] = ctx[mt][nt][r];
      }
    }
  if (w == 0 && lane < 16) {
#pragma unroll
    for (int qt = 0; qt < 3; ++qt) {
      const int q = qt * 16 + lane;
      if (q < 34) {
        const size_t idx = (size_t)(half * ROWS + b * 34 + q) * 8 + h;
        m_part[idx] = m_run[qt];
        l_part[idx] = l_run[qt];
      }
    }
  }
}

// ---------- combine the two T-halves -> ctx_bf ----------
__global__ __launch_bounds__(256) void ca_combine_kernel(
    const float* __restrict__ o_part, const float* __restrict__ m_part,
    const float* __restrict__ l_part, unsigned short* __restrict__ ctx_bf) {
  const int row = blockIdx.x, c = threadIdx.x;
#pragma unroll
  for (int h = 0; h < NHH; ++h) {
    const float m0 = m_part[(size_t)row * 8 + h];
    const float m1 = m_part[(size_t)(ROWS + row) * 8 + h];
    const float l0 = l_part[(size_t)row * 8 + h];
    const float l1 = l_part[(size_t)(ROWS + row) * 8 + h];
    const float M = fmaxf(m0, m1);
    const float w0 = __expf(m0 - M), w1 = __expf(m1 - M);
    const float denom = l0 * w0 + l1 * w1;
    const float o0 = o_part[(size_t)row * 2048 + h * 256 + c];
    const float o1 = o_part[(size_t)(ROWS + row) * 2048 + h * 256 + c];
    ctx_bf[(size_t)row * 2048 + h * 256 + c] = f2bf((o0 * w0 + o1 * w1) / denom);
  }
}

// ---------- refine pair-mean: h = relu(u_i + b1 + v_j), mean over j ----------
// uv: [ROWS][256], u = cols 0..127, v = cols 128..255.
__global__ __launch_bounds__(256) void pairmean_kernel(
    const float* __restrict__ uv, const float* __restrict__ b1,
    unsigned short* __restrict__ hbar_bf) {
  const int bp = blockIdx.x, tid = threadIdx.x;
  const int r0 = bp * KK;
  __shared__ float us[KK][132], vs[KK][132];
  __shared__ float b1s[128];
  if (tid < 128) b1s[tid] = b1[tid];
  for (int i = tid; i < KK * HIDD; i += 256) {
    const int r = i >> 7, f = i & 127;
    us[r][f] = uv[(size_t)(r0 + r) * 256 + f];
    vs[r][f] = uv[(size_t)(r0 + r) * 256 + 128 + f];
  }
  __syncthreads();
  for (int i = tid; i < KK * HIDD; i += 256) {
    const int r = i >> 7, f = i & 127;
    const float ub = us[r][f] + b1s[f];
    float s = 0.f;
#pragma unroll
    for (int j = 0; j < KK; ++j) s += fmaxf(ub + vs[j][f], 0.f);
    hbar_bf[(size_t)(r0 + r) * HIDD + f] = f2bf(s * (1.0f / 17.0f));
  }
}

static void gemm_bf(const unsigned short* X, const unsigned short* W, const float* bias,
                    const float* R, float* Yf, unsigned short* Ybf, int M, int N, int K,
                    int wstride, int relu, hipStream_t s) {
  dim3 g(N / 64, M / 64);
  gemm_bf16_kernel<<<g, 256, 0, s>>>(X, W, bias, R, Yf, Ybf, M, N, K, wstride, relu);
}
static void gemm_sk(const unsigned short* X, const unsigned short* W, float* part,
                    int M, int N, int K, int wstride, int ksplit, hipStream_t s) {
  dim3 g(N / 64, M / 64, ksplit);
  gemm_bf16_sk_kernel<<<g, 256, 0, s>>>(X, W, part, M, N, K, wstride, K / ksplit);
}

extern "C" void kernel_launch(void* const* d_in, const int* in_sizes, int n_in,
                              void* d_out, int out_size, void* d_ws, size_t ws_size,
                              hipStream_t stream) {
  const float* memory   = (const float*)d_in[0];
  const float* person_q = (const float*)d_in[1];
  const float* key_q    = (const float*)d_in[2];
  const float* sa_in_w  = (const float*)d_in[3];
  const float* sa_in_b  = (const float*)d_in[4];
  const float* sa_out_w = (const float*)d_in[5];
  const float* sa_out_b = (const float*)d_in[6];
  const float* ca_in_w  = (const float*)d_in[7];
  const float* ca_in_b  = (const float*)d_in[8];
  const float* ca_out_w = (const float*)d_in[9];
  const float* ca_out_b = (const float*)d_in[10];
  const float* ff1_w = (const float*)d_in[11];
  const float* ff1_b = (const float*)d_in[12];
  const float* ff2_w = (const float*)d_in[13];
  const float* ff2_b = (const float*)d_in[14];
  const float* ln1_w = (const float*)d_in[15];
  const float* ln1_b = (const float*)d_in[16];
  const float* ln2_w = (const float*)d_in[17];
  const float* ln2_b = (const float*)d_in[18];
  const float* ln3_w = (const float*)d_in[19];
  const float* ln3_b = (const float*)d_in[20];
  const float* r1_w1 = (const float*)d_in[21];
  const float* r1_b1 = (const float*)d_in[22];
  const float* r1_w2 = (const float*)d_in[23];
  const float* r1_b2 = (const float*)d_in[24];
  const float* r2_w1 = (const float*)d_in[25];
  const float* r2_b1 = (const float*)d_in[26];
  const float* r2_w2 = (const float*)d_in[27];
  const float* r2_b2 = (const float*)d_in[28];
  const float* fc_w  = (const float*)d_in[29];
  const float* fc_b  = (const float*)d_in[30];
  float* out = (float*)d_out;

  char* wsb = (char*)d_ws;
  size_t off = 0;
  auto alloc = [&](size_t bytes) -> char* {
    char* p = wsb + off;
    off += (bytes + 255) & ~(size_t)255;
    return p;
  };
  float* x      = (float*)alloc((size_t)ROWS * DD * 4);
  float* qkv    = (float*)alloc((size_t)ROWS * 768 * 4);
  float* parts  = (float*)alloc((size_t)4 * ROWS * DD * 4);
  float* bvo    = (float*)alloc(3 * 256 * 4);
  float* bqk    = (float*)alloc((size_t)3 * 2048 * 4);
  float* uvbuf  = (float*)alloc((size_t)ROWS * 256 * 4);
  float* o_part = (float*)alloc((size_t)2 * ROWS * 2048 * 4);
  float* m_part = (float*)alloc((size_t)2 * ROWS * 8 * 4);
  float* l_part = (float*)alloc((size_t)2 * ROWS * 8 * 4);
  unsigned short* x_bf     = (unsigned short*)alloc((size_t)ROWS * DD * 2);
  unsigned short* attn_bf  = (unsigned short*)alloc((size_t)ROWS * DD * 2);
  unsigned short* hff_bf   = (unsigned short*)alloc((size_t)ROWS * 2048 * 2);
  unsigned short* ctx_bf   = (unsigned short*)alloc((size_t)ROWS * 2048 * 2);
  unsigned short* qkeff_bf = (unsigned short*)alloc((size_t)ROWS * 2048 * 2);
  unsigned short* hbar_bf  = (unsigned short*)alloc((size_t)ROWS * HIDD * 2);
  unsigned short* mem_bf   = (unsigned short*)alloc((size_t)NB * TSEQ * DD * 2);
  unsigned short* memT     = (unsigned short*)alloc((size_t)NB * TSEQ * DD * 2);
  unsigned short* sa_in_bf  = (unsigned short*)alloc((size_t)3 * 768 * 256 * 2);
  unsigned short* sa_out_bf = (unsigned short*)alloc((size_t)3 * 256 * 256 * 2);
  unsigned short* Wqk_bf   = (unsigned short*)alloc((size_t)3 * 2048 * 256 * 2);
  unsigned short* ff1_bf   = (unsigned short*)alloc((size_t)3 * 2048 * 256 * 2);
  unsigned short* ff2_bf   = (unsigned short*)alloc((size_t)3 * 256 * 2048 * 2);
  unsigned short* Wvo_bf   = (unsigned short*)alloc((size_t)3 * 256 * 2048 * 2);
  unsigned short* rpack_bf = (unsigned short*)alloc((size_t)2 * 256 * 256 * 2);
  unsigned short* r1w2_bf  = (unsigned short*)alloc((size_t)DD * HIDD * 2);
  unsigned short* r2w2_bf  = (unsigned short*)alloc((size_t)DD * HIDD * 2);

  // ---- prep ----
  prep_mem_kernel<<<NB * 64, 256, 0, stream>>>(memory, mem_bf, memT);
  CvtJobs8 jobs;
  jobs.j[0] = {sa_in_w,  sa_in_bf,  3 * 768 * 256};
  jobs.j[1] = {sa_out_w, sa_out_bf, 3 * 256 * 256};
  jobs.j[2] = {ff1_w,    ff1_bf,    3 * 2048 * 256};
  jobs.j[3] = {ff2_w,    ff2_bf,    3 * 256 * 2048};
  jobs.j[4] = {r1_w2,    r1w2_bf,   DD * HIDD};
  jobs.j[5] = {r2_w2,    r2w2_bf,   DD * HIDD};
  jobs.j[6] = {r1_w2,    r1w2_bf,   0};
  jobs.j[7] = {r2_w2,    r2w2_bf,   0};
  cvt_multi_kernel<<<1024, 256, 0, stream>>>(jobs);
  wqkvo_kernel<<<12800, 256, 0, stream>>>(ca_in_w, ca_out_w, r1_w1, r2_w1,
                                          Wqk_bf, Wvo_bf, rpack_bf);
  prep_small_kernel<<<ROWS + 24 + 3, 256, 0, stream>>>(
      person_q, key_q, ca_in_w, ca_in_b, ca_out_w, ca_out_b, x, x_bf, bqk, bvo);

  for (int l = 0; l < LL; ++l) {
    // --- self-attention ---
    gemm_bf(x_bf, sa_in_bf + (size_t)l * 768 * 256, sa_in_b + l * 768, nullptr,
            qkv, nullptr, ROWS, 768, 256, 256, 0, stream);
    sa_attn_kernel<<<512, 64, 0, stream>>>(qkv, attn_bf);
    gemm_sk(attn_bf, sa_out_bf + (size_t)l * 256 * 256, parts,
            ROWS, 256, 256, 256, 2, stream);
    ln_red_kernel<<<ROWS, 256, 0, stream>>>(x, parts, 2, sa_out_b + l * 256,
                                            ln1_w + l * 256, ln1_b + l * 256, x, x_bf);
    // --- cross-attention: qk_eff = x @ Wqk^T + bqk (scale folded) ---
    gemm_bf(x_bf, Wqk_bf + (size_t)l * 2048 * 256, bqk + l * 2048, nullptr,
            nullptr, qkeff_bf, ROWS, 2048, 256, 256, 0, stream);
    ca_fused_kernel<<<512, 256, 0, stream>>>(qkeff_bf, mem_bf, memT, o_part, m_part, l_part);
    ca_combine_kernel<<<ROWS, 256, 0, stream>>>(o_part, m_part, l_part, ctx_bf);
    gemm_sk(ctx_bf, Wvo_bf + (size_t)l * 256 * 2048, parts,
            ROWS, 256, 2048, 2048, 4, stream);
    ln_red_kernel<<<ROWS, 256, 0, stream>>>(x, parts, 4, bvo + l * 256,
                                            ln2_w + l * 256, ln2_b + l * 256, x, x_bf);
    // --- feed-forward ---
    gemm_bf(x_bf, ff1_bf + (size_t)l * 2048 * 256, ff1_b + l * 2048, nullptr,
            nullptr, hff_bf, ROWS, 2048, 256, 256, 1, stream);
    gemm_sk(hff_bf, ff2_bf + (size_t)l * 256 * 2048, parts,
            ROWS, 256, 2048, 2048, 4, stream);
    ln_red_kernel<<<ROWS, 256, 0, stream>>>(x, parts, 4, ff2_b + l * 256,
                                            ln3_w + l * 256, ln3_b + l * 256, x, x_bf);
  }

  // --- two refine blocks (bf16 MFMA, packed u|v weight) ---
  const unsigned short* rw2_bf[2] = {r1w2_bf, r2w2_bf};
  const float* rb1[2] = {r1_b1, r2_b1};
  const float* rb2[2] = {r1_b2, r2_b2};
  for (int r = 0; r < 2; ++r) {
    gemm_bf(x_bf, rpack_bf + (size_t)r * 65536, nullptr, nullptr, uvbuf, nullptr,
            ROWS, 256, 256, 256, 0, stream);
    pairmean_kernel<<<64, 256, 0, stream>>>(uvbuf, rb1[r], hbar_bf);
    gemm_bf(hbar_bf, rw2_bf[r], rb2[r], x, x, x_bf,
            ROWS, 256, 128, 128, 0, stream);
  }

  // --- final fc ---
  fc_kernel<<<ROWS / 4, 256, 0, stream>>>(x, fc_w, fc_b, out);
}